// Round 3
// baseline (13984.909 us; speedup 1.0000x reference)
//
#include <hip/hip_runtime.h>
#include <hip/hip_cooperative_groups.h>

namespace cg = cooperative_groups;

#define B_ 4
#define T_ 250
#define U_ 120
#define D_ 512
#define G_ 2048   // 4*D (gates)
#define O_ 1024   // odim

typedef __attribute__((ext_vector_type(8))) short bf16x8;
typedef __attribute__((ext_vector_type(4))) float f32x4;
typedef __attribute__((ext_vector_type(4))) unsigned int ui4;

__device__ __forceinline__ float tanh_fast(float x){
  float e = __expf(2.f*x);
  return 1.f - 2.f/(e + 1.f);
}
__device__ __forceinline__ float sigmoid_fast(float x){
  return 1.f/(1.f + __expf(-x));
}
__device__ __forceinline__ unsigned short f2bf(float x){
  unsigned int u = __float_as_uint(x);
  unsigned int r = (u + 0x7FFFu + ((u >> 16) & 1u)) >> 16;
  return (unsigned short)r;
}

__global__ void zero_ws_k(float* p, int n){
  int i = blockIdx.x*256 + threadIdx.x;
  if (i < n) p[i] = 0.f;
}

__global__ void gather_embed_k(const int* __restrict__ ys, const float* __restrict__ embed,
                               float* __restrict__ eys){
  int i = blockIdx.x*256 + threadIdx.x;
  if (i < B_*U_*D_){
    int r = i >> 9, k = i & 511;
    eys[i] = embed[ys[r]*D_ + k];
  }
}

// Wt[k*2048 + j] = W[j*ldw + k], j<2048, k<512. grid (64,16), block (32,8)
__global__ void transpose_k(const float* __restrict__ W, int ldw, float* __restrict__ Wt){
  __shared__ float t[32][33];
  int j0 = blockIdx.x*32, k0 = blockIdx.y*32;
  int tx = threadIdx.x, ty = threadIdx.y;
  for (int r=0;r<32;r+=8) t[ty+r][tx] = W[(size_t)(j0+ty+r)*ldw + k0 + tx];
  __syncthreads();
  for (int r=0;r<32;r+=8) Wt[(size_t)(k0+ty+r)*G_ + j0 + tx] = t[tx][ty+r];
}

// ---------- 64x64-tile f32 GEMMs for precompute ----------
// C[m][n] = bias[n] + sum_k A[m*lda+k]*B[n*ldb+k]
__global__ __launch_bounds__(256) void gemm64_nt_k(
  const float* __restrict__ A, int lda, const float* __restrict__ B, int ldb,
  const float* __restrict__ bias, float* __restrict__ C, int ldc,
  int M, int N, int K)
{
  __shared__ float As[16][65], Bs[16][65];
  int tid = threadIdx.x;
  int m0 = blockIdx.y*64, n0 = blockIdx.x*64;
  int tx = tid & 15, ty = tid >> 4;
  float acc[4][4] = {};
  for (int k0 = 0; k0 < K; k0 += 16){
#pragma unroll
    for (int i=0;i<4;i++){
      int e = tid + 256*i;
      int mm = e >> 4, kk = e & 15;
      int mg = m0 + mm;
      As[kk][mm] = (mg < M) ? A[(size_t)mg*lda + k0 + kk] : 0.f;
      int ng = n0 + mm;
      Bs[kk][mm] = (ng < N) ? B[(size_t)ng*ldb + k0 + kk] : 0.f;
    }
    __syncthreads();
#pragma unroll
    for (int kk=0;kk<16;kk++){
      float av[4], bv[4];
#pragma unroll
      for (int i=0;i<4;i++) av[i] = As[kk][ty*4+i];
#pragma unroll
      for (int j=0;j<4;j++) bv[j] = Bs[kk][tx*4+j];
#pragma unroll
      for (int i=0;i<4;i++)
#pragma unroll
        for (int j=0;j<4;j++) acc[i][j] += av[i]*bv[j];
    }
    __syncthreads();
  }
#pragma unroll
  for (int i=0;i<4;i++){
    int m = m0 + ty*4 + i;
    if (m < M){
#pragma unroll
      for (int j=0;j<4;j++){
        int n = n0 + tx*4 + j;
        if (n < N) C[(size_t)m*ldc + n] = acc[i][j] + (bias ? bias[n] : 0.f);
      }
    }
  }
}

// C[m][n] = bias[n] + sum_k A[m*lda+k]*B[k*ldb+n]
__global__ __launch_bounds__(256) void gemm64_nn_k(
  const float* __restrict__ A, int lda, const float* __restrict__ B, int ldb,
  const float* __restrict__ bias, float* __restrict__ C, int ldc,
  int M, int N, int K)
{
  __shared__ float As[16][65], Bs[16][65];
  int tid = threadIdx.x;
  int m0 = blockIdx.y*64, n0 = blockIdx.x*64;
  int tx = tid & 15, ty = tid >> 4;
  float acc[4][4] = {};
  for (int k0 = 0; k0 < K; k0 += 16){
#pragma unroll
    for (int i=0;i<4;i++){
      int e = tid + 256*i;
      int mm = e >> 4, kk = e & 15;
      int mg = m0 + mm;
      As[kk][mm] = (mg < M) ? A[(size_t)mg*lda + k0 + kk] : 0.f;
      int nn = e & 63, kk2 = e >> 6;
      int ng = n0 + nn;
      Bs[kk2][nn] = (ng < N) ? B[(size_t)(k0+kk2)*ldb + ng] : 0.f;
    }
    __syncthreads();
#pragma unroll
    for (int kk=0;kk<16;kk++){
      float av[4], bv[4];
#pragma unroll
      for (int i=0;i<4;i++) av[i] = As[kk][ty*4+i];
#pragma unroll
      for (int j=0;j<4;j++) bv[j] = Bs[kk][tx*4+j];
#pragma unroll
      for (int i=0;i<4;i++)
#pragma unroll
        for (int j=0;j<4;j++) acc[i][j] += av[i]*bv[j];
    }
    __syncthreads();
  }
#pragma unroll
  for (int i=0;i<4;i++){
    int m = m0 + ty*4 + i;
    if (m < M){
#pragma unroll
      for (int j=0;j<4;j++){
        int n = n0 + tx*4 + j;
        if (n < N) C[(size_t)m*ldc + n] = acc[i][j] + (bias ? bias[n] : 0.f);
      }
    }
  }
}

// ---------- cooperative persistent scan kernel ----------
// grid 256 x 256 threads. 3 grid syncs per step.
__global__ __launch_bounds__(256) void scan_k(
    float* __restrict__ z0, float* __restrict__ c0,
    float* __restrict__ z1, float* __restrict__ c1,
    float* __restrict__ q,  float* __restrict__ e,
    float* __restrict__ partial0, float* __restrict__ partial1,
    const float* __restrict__ pre_enc, const float* __restrict__ pre0,
    const float* __restrict__ hsW0,
    const float* __restrict__ Wt_hh0, const float* __restrict__ Wt_ih1,
    const float* __restrict__ Wt_hh1, const float* __restrict__ W_att_dec,
    const float* __restrict__ gvec, const int* __restrict__ hlens,
    const float* __restrict__ b_ih0, const float* __restrict__ b_hh0,
    const float* __restrict__ b_ih1, const float* __restrict__ b_hh1,
    float* __restrict__ h_dec)
{
  cg::grid_group grid = cg::this_grid();
  int blk = blockIdx.x, tid = threadIdx.x;
  int lane = tid & 63, wvid = tid >> 6;
  __shared__ float zs[2048];
  __shared__ float red[16][4][17];
  __shared__ float w_sm[256];
  __shared__ float r2[32][9];
  __shared__ float gbuf[64];
  __shared__ float sred[16];

  for (int u = 0; u < U_; ++u){
    // ---------------- Phase A: e rows + recurrent partials ----------------
    {
      const float* zsrc = (blk < 128) ? z0 : z1;
      for (int i = tid; i < 2048; i += 256) zs[i] = zsrc[i];
      __syncthreads();
      int j0 = (blk & 127) * 16;
      const float* Wt = (blk < 128) ? Wt_hh0 : Wt_hh1;
      float* par = (blk < 128) ? partial0 : partial1;
      int c = tid & 15, kg = tid >> 4;
      float a0=0.f,a1=0.f,a2=0.f,a3=0.f;
      const float* wp = Wt + (size_t)(kg*32)*G_ + j0 + c;
      for (int k = kg*32; k < kg*32+32; ++k){
        float wvv = *wp; wp += G_;
        a0 += zs[k]*wvv; a1 += zs[512+k]*wvv;
        a2 += zs[1024+k]*wvv; a3 += zs[1536+k]*wvv;
      }
      red[c][0][kg]=a0; red[c][1][kg]=a1; red[c][2][kg]=a2; red[c][3][kg]=a3;
      // e: one row per wave; 1024 waves cover 1000 rows
      int row = blk*4 + wvid;
      if (row < B_*T_){
        int b = row / T_, t = row - b*T_;
        const float* pe = pre_enc + (size_t)row*512 + lane*8;
        const float* qp = q + b*512 + lane*8;
        const float* gp = gvec + lane*8;
        float s = 0.f;
#pragma unroll
        for (int i=0;i<8;i++) s += tanh_fast(pe[i] + qp[i]) * gp[i];
#pragma unroll
        for (int off=32; off; off>>=1) s += __shfl_xor(s, off);
        if (lane==0) e[row] = (t < hlens[b]) ? s : -1e30f;
      }
      __syncthreads();
      if (tid < 64){
        int cc = tid & 15, b = tid >> 4;
        float s = 0.f;
#pragma unroll
        for (int k2=0;k2<16;k2++) s += red[cc][b][k2];
        par[b*G_ + j0 + cc] = s;
      }
    }
    grid.sync();
    // ---------------- Phase B: softmax + gates0 -> z0', c0' ----------------
    {
      int b = blk >> 6, d0 = (blk & 63) * 8;
      float v = (tid < T_) ? e[b*T_ + tid] : -1e30f;
      float m = v;
#pragma unroll
      for (int off=32; off; off>>=1) m = fmaxf(m, __shfl_xor(m, off));
      if (lane==0) sred[wvid] = m;
      __syncthreads();
      if (tid==0){ sred[0] = fmaxf(fmaxf(sred[0],sred[1]),fmaxf(sred[2],sred[3])); }
      __syncthreads();
      float mx = sred[0];
      float p = (tid < T_) ? __expf(v - mx) : 0.f;
      float ssum = p;
#pragma unroll
      for (int off=32; off; off>>=1) ssum += __shfl_xor(ssum, off);
      if (lane==0) sred[8+wvid] = ssum;
      __syncthreads();
      if (tid==0){ sred[1] = sred[8]+sred[9]+sred[10]+sred[11]; }
      __syncthreads();
      float inv = 1.f / sred[1];
      if (tid < 256) w_sm[tid] = (tid < T_) ? p * inv : 0.f;
      __syncthreads();
      int c = tid & 31, tg = tid >> 5;
      int col = (c >> 3)*512 + d0 + (c & 7);
      const float* hw = hsW0 + (size_t)b*T_*G_ + col;
      float a = 0.f;
      for (int t = tg; t < T_; t += 8) a += w_sm[t] * hw[(size_t)t*G_];
      r2[c][tg] = a;
      __syncthreads();
      if (tid < 32){
        float s = 0.f;
#pragma unroll
        for (int k2=0;k2<8;k2++) s += r2[tid][k2];
        int colv = (tid >> 3)*512 + d0 + (tid & 7);
        gbuf[tid] = s + partial0[b*G_ + colv] + pre0[(size_t)(b*U_+u)*G_ + colv]
                      + b_ih0[colv] + b_hh0[colv];
      }
      __syncthreads();
      if (tid < 8){
        int d = d0 + tid;
        float ig = sigmoid_fast(gbuf[tid]);
        float fg = sigmoid_fast(gbuf[8+tid]);
        float gg = tanh_fast(gbuf[16+tid]);
        float og = sigmoid_fast(gbuf[24+tid]);
        float cn = fg * c0[b*512+d] + ig * gg;
        float hn = og * tanh_fast(cn);
        c0[b*512+d] = cn;
        z0[b*512+d] = hn;
      }
    }
    grid.sync();
    // ---------------- Phase C: lstm1 -> z1', c1', h_dec; q' ----------------
    {
      for (int i = tid; i < 2048; i += 256) zs[i] = z0[i];
      __syncthreads();
      if (blk < 128){
        int d0 = blk * 4;
        int c = tid & 15, kg = tid >> 4;
        int col = (c >> 2)*512 + d0 + (c & 3);
        float a0=0.f,a1=0.f,a2=0.f,a3=0.f;
        const float* wp = Wt_ih1 + (size_t)(kg*32)*G_ + col;
        for (int k = kg*32; k < kg*32+32; ++k){
          float wvv = *wp; wp += G_;
          a0 += zs[k]*wvv; a1 += zs[512+k]*wvv;
          a2 += zs[1024+k]*wvv; a3 += zs[1536+k]*wvv;
        }
        red[c][0][kg]=a0; red[c][1][kg]=a1; red[c][2][kg]=a2; red[c][3][kg]=a3;
        __syncthreads();
        if (tid < 64){
          int cc = tid & 15, b = tid >> 4;
          float s = 0.f;
#pragma unroll
          for (int k2=0;k2<16;k2++) s += red[cc][b][k2];
          int colv = (cc >> 2)*512 + d0 + (cc & 3);
          gbuf[b*16 + cc] = s + partial1[b*G_ + colv] + b_ih1[colv] + b_hh1[colv];
        }
        __syncthreads();
        if (tid < 16){
          int b = tid >> 2, dd = tid & 3;
          int d = d0 + dd;
          float ig = sigmoid_fast(gbuf[b*16 + 0*4 + dd]);
          float fg = sigmoid_fast(gbuf[b*16 + 1*4 + dd]);
          float gg = tanh_fast(gbuf[b*16 + 2*4 + dd]);
          float og = sigmoid_fast(gbuf[b*16 + 3*4 + dd]);
          float cn = fg * c1[b*512+d] + ig * gg;
          float hn = og * tanh_fast(cn);
          c1[b*512+d] = cn;
          z1[b*512+d] = hn;
          h_dec[(size_t)(b*U_+u)*512 + d] = hn;
        }
      } else {
        int a0q = (blk - 128) * 4;
        if (tid < 64){
          int c = tid & 3, kg = tid >> 2;
          float a0=0.f,a1=0.f,a2=0.f,a3=0.f;
          const float* wp = W_att_dec + (size_t)(kg*32)*512 + a0q + c;
          for (int k = kg*32; k < kg*32+32; ++k){
            float wvv = *wp; wp += 512;
            a0 += zs[k]*wvv; a1 += zs[512+k]*wvv;
            a2 += zs[1024+k]*wvv; a3 += zs[1536+k]*wvv;
          }
          red[c][0][kg]=a0; red[c][1][kg]=a1; red[c][2][kg]=a2; red[c][3][kg]=a3;
        }
        __syncthreads();
        if (tid < 16){
          int c = tid & 3, b = tid >> 2;
          float s = 0.f;
#pragma unroll
          for (int k2=0;k2<16;k2++) s += red[c][b][k2];
          q[b*512 + a0q + c] = s;
        }
      }
    }
    grid.sync();
  }
}

// ---------- fallback f32 joint ----------
#define JKC 16
__global__ __launch_bounds__(256) void joint_k(
    const float* __restrict__ henc, const float* __restrict__ hdec,
    const float* __restrict__ Wout, const float* __restrict__ bout,
    float* __restrict__ out)
{
  int ot = blockIdx.x;
  int t  = blockIdx.y;
  int b  = blockIdx.z;
  __shared__ float As[128][JKC+1];
  __shared__ float Bs[128][JKC+1];
  int tid = threadIdx.x;
  int tx = tid & 15, ty = tid >> 4;
  float acc[8][8] = {};
  const float* henc_row = henc + (size_t)(b*T_ + t)*512;
  for (int k0 = 0; k0 < 512; k0 += JKC){
#pragma unroll
    for (int i=0;i<8;i++){
      int e = tid*8+i; int r = e>>4, kk = e&15;
      float hv = henc_row[k0+kk];
      float dv = (r < U_) ? hdec[(size_t)(b*U_ + r)*512 + k0 + kk] : 0.f;
      As[r][kk] = tanh_fast(hv+dv);
      Bs[r][kk] = Wout[(size_t)(ot*128 + r)*512 + k0 + kk];
    }
    __syncthreads();
#pragma unroll
    for (int kk=0; kk<JKC; kk++){
      float a[8], bb[8];
#pragma unroll
      for (int i=0;i<8;i++) a[i]  = As[ty*8+i][kk];
#pragma unroll
      for (int j=0;j<8;j++) bb[j] = Bs[tx*8+j][kk];
#pragma unroll
      for (int i=0;i<8;i++)
#pragma unroll
        for (int j=0;j<8;j++)
          acc[i][j] += a[i]*bb[j];
    }
    __syncthreads();
  }
  int o0 = ot*128 + tx*8;
#pragma unroll
  for (int i=0;i<8;i++){
    int u = ty*8 + i;
    if (u < U_){
      float* op = out + ((size_t)(b*T_ + t)*U_ + u)*O_ + o0;
#pragma unroll
      for (int j=0;j<8;j++) op[j] = acc[i][j] + bout[o0+j];
    }
  }
}

// ---------- bf16 MFMA joint path ----------
__global__ __launch_bounds__(256) void tanh_pack_k(
    const float* __restrict__ henc, const float* __restrict__ hdec,
    unsigned short* __restrict__ P)
{
  int i = blockIdx.x*256 + threadIdx.x;
  if (i >= B_*T_*U_*512/8) return;
  int e = i*8;
  int k = e & 511;
  int r = e >> 9;
  int u = r % U_;
  int bt = r / U_;
  int b = bt / T_;
  const float* hp = henc + (size_t)bt*512 + k;
  const float* dp = hdec + (size_t)(b*U_ + u)*512 + k;
  unsigned int w[4];
#pragma unroll
  for (int j=0;j<4;j++){
    unsigned short lo = f2bf(tanh_fast(hp[2*j]   + dp[2*j]));
    unsigned short hi = f2bf(tanh_fast(hp[2*j+1] + dp[2*j+1]));
    w[j] = (unsigned int)lo | ((unsigned int)hi << 16);
  }
  ui4* dst = (ui4*)(P + e);
  *dst = ui4{w[0], w[1], w[2], w[3]};
}

__global__ __launch_bounds__(256) void wconv_k(const float* __restrict__ W,
                                               unsigned short* __restrict__ Wb, int n8){
  int i = blockIdx.x*256 + threadIdx.x;
  if (i >= n8) return;
  int e = i*8;
  unsigned int w[4];
#pragma unroll
  for (int j=0;j<4;j++){
    unsigned short lo = f2bf(W[e+2*j]);
    unsigned short hi = f2bf(W[e+2*j+1]);
    w[j] = (unsigned int)lo | ((unsigned int)hi << 16);
  }
  *(ui4*)(Wb + e) = ui4{w[0], w[1], w[2], w[3]};
}

__global__ __launch_bounds__(256) void joint_mfma_k(
    const unsigned short* __restrict__ P,
    const unsigned short* __restrict__ Wb,
    const float* __restrict__ bout,
    float* __restrict__ out)
{
  __shared__ unsigned short As[128*64];
  __shared__ unsigned short Bs[128*64];
  int tid = threadIdx.x;
  int lane = tid & 63;
  int w = tid >> 6, wr = w >> 1, wc = w & 1;
  int o0 = blockIdx.x * 128;
  int t = blockIdx.y, b = blockIdx.z;
  int bt = b*T_ + t;
  const char* Pbase = (const char*)(P + (size_t)bt*U_*512);
  const char* Wbase = (const char*)(Wb + (size_t)o0*512);

  f32x4 acc[4][4] = {};

  for (int k0 = 0; k0 < 512; k0 += 64){
    __syncthreads();
#pragma unroll
    for (int j=0;j<4;j++){
      int pos = (j*256 + tid)*16;
      int row = pos >> 7;
      int inrow = pos & 127;
      int srcin = inrow ^ ((row & 7) << 4);
      int arow = row < U_ ? row : (U_-1);
      __builtin_amdgcn_global_load_lds(
        (const __attribute__((address_space(1))) void*)(Pbase + (size_t)arow*1024 + k0*2 + srcin),
        (__attribute__((address_space(3))) void*)((char*)As + pos), 16, 0, 0);
      __builtin_amdgcn_global_load_lds(
        (const __attribute__((address_space(1))) void*)(Wbase + (size_t)row*1024 + k0*2 + srcin),
        (__attribute__((address_space(3))) void*)((char*)Bs + pos), 16, 0, 0);
    }
    __syncthreads();
#pragma unroll
    for (int kk=0; kk<2; kk++){
      bf16x8 a[4], bb[4];
#pragma unroll
      for (int m=0;m<4;m++){
        int row = wr*64 + m*16 + (lane & 15);
        int inrow = (kk*64 + (lane >> 4)*16) ^ ((row & 7) << 4);
        a[m] = *(const bf16x8*)((const char*)As + row*128 + inrow);
      }
#pragma unroll
      for (int n=0;n<4;n++){
        int row = wc*64 + n*16 + (lane & 15);
        int inrow = (kk*64 + (lane >> 4)*16) ^ ((row & 7) << 4);
        bb[n] = *(const bf16x8*)((const char*)Bs + row*128 + inrow);
      }
#pragma unroll
      for (int m=0;m<4;m++)
#pragma unroll
        for (int n=0;n<4;n++)
          acc[m][n] = __builtin_amdgcn_mfma_f32_16x16x32_bf16(a[m], bb[n], acc[m][n], 0, 0, 0);
    }
  }
#pragma unroll
  for (int n=0;n<4;n++){
    int o = o0 + wc*64 + n*16 + (lane & 15);
    float bias = bout[o];
#pragma unroll
    for (int m=0;m<4;m++){
      int ubase = wr*64 + m*16 + ((lane >> 4) << 2);
#pragma unroll
      for (int r=0;r<4;r++){
        int u = ubase + r;
        if (u < U_)
          out[((size_t)bt*U_ + u)*O_ + o] = acc[m][n][r] + bias;
      }
    }
  }
}

extern "C" void kernel_launch(void* const* d_in, const int* in_sizes, int n_in,
                              void* d_out, int out_size, void* d_ws, size_t ws_size,
                              hipStream_t stream) {
  const float* hs       = (const float*)d_in[0];
  const int*   ys       = (const int*)  d_in[1];
  const int*   hlens    = (const int*)  d_in[2];
  const float* embed    = (const float*)d_in[3];
  const float* W_ih0    = (const float*)d_in[4];
  const float* b_ih0    = (const float*)d_in[5];
  const float* W_hh0    = (const float*)d_in[6];
  const float* b_hh0    = (const float*)d_in[7];
  const float* W_ih1    = (const float*)d_in[8];
  const float* b_ih1    = (const float*)d_in[9];
  const float* W_hh1    = (const float*)d_in[10];
  const float* b_hh1    = (const float*)d_in[11];
  const float* W_att_enc= (const float*)d_in[12];
  const float* b_att_enc= (const float*)d_in[13];
  const float* W_att_dec= (const float*)d_in[14];
  const float* gvec     = (const float*)d_in[15];
  const float* W_lin_enc= (const float*)d_in[16];
  const float* b_lin_enc= (const float*)d_in[17];
  const float* W_lin_dec= (const float*)d_in[18];
  const float* W_lin_out= (const float*)d_in[19];
  const float* b_lin_out= (const float*)d_in[20];
  float* out = (float*)d_out;

  float* w = (float*)d_ws;
  // ws layout (float offsets)
  float* z0    = w;               // 2048 (4x512)
  float* c0    = w + 2048;
  float* z1    = w + 4096;
  float* c1    = w + 6144;
  float* q     = w + 8192;        // 2048
  float* e     = w + 10240;       // 1000 (pad 1024)
  float* partial0 = w + 11264;    // 8192
  float* partial1 = w + 19456;    // 8192 -> 27648
  float* eys   = w + 27648;       // 245760
  float* pre_enc = w + 273408;    // 512000
  float* pre0    = w + 785408;    // 983040
  float* henc    = w + 1768448;   // 512000
  float* h_dec   = w + 2280448;   // 245760
  float* hdec_p  = w + 2526208;   // 245760
  float* Wt_hh0  = w + 2771968;   // 1048576
  float* Wt_ih1  = w + 3820544;   // 1048576
  float* Wt_hh1  = w + 4869120;   // 1048576 -> 5917696
  // hsW0 overlaps the Pbf region (dead until after the scan)
  float* hsW0 = w + 6959104;                       // 2,048,000 floats
  unsigned short* Pbf = (unsigned short*)(w + 6959104);
  unsigned short* Wbf = (unsigned short*)(w + 6959104 + 30720000);
  const size_t ws_needed = (size_t)(6959104 + 30720000 + 262144) * 4;

  zero_ws_k<<<108, 256, 0, stream>>>(w, 27648);
  gather_embed_k<<<(B_*U_*D_ + 255)/256, 256, 0, stream>>>(ys, embed, eys);
  // pre_enc = hs @ W_att_enc + b (nn)
  gemm64_nn_k<<<dim3(8, 16), 256, 0, stream>>>(hs, 512, W_att_enc, 512, b_att_enc,
                                               pre_enc, 512, B_*T_, 512, 512);
  // pre0 = eys @ W_ih0[:, :512]^T
  gemm64_nt_k<<<dim3(32, 8), 256, 0, stream>>>(eys, 512, W_ih0, 1024, nullptr,
                                               pre0, 2048, B_*U_, 2048, 512);
  // hsW0 = hs @ W_ih0[:, 512:]^T
  gemm64_nt_k<<<dim3(32, 16), 256, 0, stream>>>(hs, 512, W_ih0 + 512, 1024, nullptr,
                                                hsW0, 2048, B_*T_, 2048, 512);
  // henc = hs @ W_lin_enc^T + b
  gemm64_nt_k<<<dim3(8, 16), 256, 0, stream>>>(hs, 512, W_lin_enc, 512, b_lin_enc,
                                               henc, 512, B_*T_, 512, 512);
  transpose_k<<<dim3(64,16), dim3(32,8), 0, stream>>>(W_hh0, 512, Wt_hh0);
  transpose_k<<<dim3(64,16), dim3(32,8), 0, stream>>>(W_ih1, 512, Wt_ih1);
  transpose_k<<<dim3(64,16), dim3(32,8), 0, stream>>>(W_hh1, 512, Wt_hh1);

  // cooperative scan
  {
    void* args[] = {
      (void*)&z0, (void*)&c0, (void*)&z1, (void*)&c1, (void*)&q, (void*)&e,
      (void*)&partial0, (void*)&partial1, (void*)&pre_enc, (void*)&pre0,
      (void*)&hsW0, (void*)&Wt_hh0, (void*)&Wt_ih1, (void*)&Wt_hh1,
      (void*)&W_att_dec, (void*)&gvec, (void*)&hlens,
      (void*)&b_ih0, (void*)&b_hh0, (void*)&b_ih1, (void*)&b_hh1,
      (void*)&h_dec
    };
    hipLaunchCooperativeKernel((const void*)scan_k, dim3(256), dim3(256),
                               args, 0, stream);
  }

  // hdec = h_dec @ W_lin_dec^T
  gemm64_nt_k<<<dim3(8, 8), 256, 0, stream>>>(h_dec, 512, W_lin_dec, 512, nullptr,
                                              hdec_p, 512, B_*U_, 512, 512);
  if (ws_size >= ws_needed){
    tanh_pack_k<<<(B_*T_*U_*512/8 + 255)/256, 256, 0, stream>>>(henc, hdec_p, Pbf);
    wconv_k<<<(O_*512/8 + 255)/256, 256, 0, stream>>>(W_lin_out, Wbf, O_*512/8);
    joint_mfma_k<<<dim3(8, T_, B_), 256, 0, stream>>>(Pbf, Wbf, b_lin_out, out);
  } else {
    joint_k<<<dim3(8, T_, B_), 256, 0, stream>>>(henc, hdec_p, W_lin_out, b_lin_out, out);
  }
}

// Round 4
// 11805.095 us; speedup vs baseline: 1.1847x; 1.1847x over previous
//
#include <hip/hip_runtime.h>
#include <hip/hip_cooperative_groups.h>

namespace cg = cooperative_groups;

#define B_ 4
#define T_ 250
#define U_ 120
#define D_ 512
#define G_ 2048   // 4*D (gates)
#define O_ 1024   // odim

typedef __attribute__((ext_vector_type(8))) short bf16x8;
typedef __attribute__((ext_vector_type(4))) float f32x4;
typedef __attribute__((ext_vector_type(4))) unsigned int ui4;

__device__ __forceinline__ float tanh_fast(float x){
  float e = __expf(2.f*x);
  return 1.f - 2.f/(e + 1.f);
}
__device__ __forceinline__ float sigmoid_fast(float x){
  return 1.f/(1.f + __expf(-x));
}
__device__ __forceinline__ unsigned short f2bf(float x){
  unsigned int u = __float_as_uint(x);
  unsigned int r = (u + 0x7FFFu + ((u >> 16) & 1u)) >> 16;
  return (unsigned short)r;
}

__global__ void gather_embed_k(const int* __restrict__ ys, const float* __restrict__ embed,
                               float* __restrict__ eys){
  int i = blockIdx.x*256 + threadIdx.x;
  if (i < B_*U_*D_){
    int r = i >> 9, k = i & 511;
    eys[i] = embed[ys[r]*D_ + k];
  }
}

// ---------- 64x64-tile f32 GEMMs for precompute ----------
// C[m][n] = bias[n] + sum_k A[m*lda+k]*B[n*ldb+k]
__global__ __launch_bounds__(256) void gemm64_nt_k(
  const float* __restrict__ A, int lda, const float* __restrict__ B, int ldb,
  const float* __restrict__ bias, float* __restrict__ C, int ldc,
  int M, int N, int K)
{
  __shared__ float As[16][65], Bs[16][65];
  int tid = threadIdx.x;
  int m0 = blockIdx.y*64, n0 = blockIdx.x*64;
  int tx = tid & 15, ty = tid >> 4;
  float acc[4][4] = {};
  for (int k0 = 0; k0 < K; k0 += 16){
#pragma unroll
    for (int i=0;i<4;i++){
      int e = tid + 256*i;
      int mm = e >> 4, kk = e & 15;
      int mg = m0 + mm;
      As[kk][mm] = (mg < M) ? A[(size_t)mg*lda + k0 + kk] : 0.f;
      int ng = n0 + mm;
      Bs[kk][mm] = (ng < N) ? B[(size_t)ng*ldb + k0 + kk] : 0.f;
    }
    __syncthreads();
#pragma unroll
    for (int kk=0;kk<16;kk++){
      float av[4], bv[4];
#pragma unroll
      for (int i=0;i<4;i++) av[i] = As[kk][ty*4+i];
#pragma unroll
      for (int j=0;j<4;j++) bv[j] = Bs[kk][tx*4+j];
#pragma unroll
      for (int i=0;i<4;i++)
#pragma unroll
        for (int j=0;j<4;j++) acc[i][j] += av[i]*bv[j];
    }
    __syncthreads();
  }
#pragma unroll
  for (int i=0;i<4;i++){
    int m = m0 + ty*4 + i;
    if (m < M){
#pragma unroll
      for (int j=0;j<4;j++){
        int n = n0 + tx*4 + j;
        if (n < N) C[(size_t)m*ldc + n] = acc[i][j] + (bias ? bias[n] : 0.f);
      }
    }
  }
}

// C[m][n] = bias[n] + sum_k A[m*lda+k]*B[k*ldb+n]
__global__ __launch_bounds__(256) void gemm64_nn_k(
  const float* __restrict__ A, int lda, const float* __restrict__ B, int ldb,
  const float* __restrict__ bias, float* __restrict__ C, int ldc,
  int M, int N, int K)
{
  __shared__ float As[16][65], Bs[16][65];
  int tid = threadIdx.x;
  int m0 = blockIdx.y*64, n0 = blockIdx.x*64;
  int tx = tid & 15, ty = tid >> 4;
  float acc[4][4] = {};
  for (int k0 = 0; k0 < K; k0 += 16){
#pragma unroll
    for (int i=0;i<4;i++){
      int e = tid + 256*i;
      int mm = e >> 4, kk = e & 15;
      int mg = m0 + mm;
      As[kk][mm] = (mg < M) ? A[(size_t)mg*lda + k0 + kk] : 0.f;
      int nn = e & 63, kk2 = e >> 6;
      int ng = n0 + nn;
      Bs[kk2][nn] = (ng < N) ? B[(size_t)(k0+kk2)*ldb + ng] : 0.f;
    }
    __syncthreads();
#pragma unroll
    for (int kk=0;kk<16;kk++){
      float av[4], bv[4];
#pragma unroll
      for (int i=0;i<4;i++) av[i] = As[kk][ty*4+i];
#pragma unroll
      for (int j=0;j<4;j++) bv[j] = Bs[kk][tx*4+j];
#pragma unroll
      for (int i=0;i<4;i++)
#pragma unroll
        for (int j=0;j<4;j++) acc[i][j] += av[i]*bv[j];
    }
    __syncthreads();
  }
#pragma unroll
  for (int i=0;i<4;i++){
    int m = m0 + ty*4 + i;
    if (m < M){
#pragma unroll
      for (int j=0;j<4;j++){
        int n = n0 + tx*4 + j;
        if (n < N) C[(size_t)m*ldc + n] = acc[i][j] + (bias ? bias[n] : 0.f);
      }
    }
  }
}

// ---------- cooperative LDS-resident scan ----------
// 256 blocks x 256 threads. Block bk owns d = {2bk, 2bk+1}. All weights in LDS.
__global__ __launch_bounds__(256) void scan_k(
    float* __restrict__ z0, float* __restrict__ z1,
    float* __restrict__ q,  float* __restrict__ e,
    const float* __restrict__ pre_enc, const float* __restrict__ pre0,
    const float* __restrict__ hsW0,
    const float* __restrict__ W_hh0, const float* __restrict__ W_ih1,
    const float* __restrict__ W_hh1, const float* __restrict__ W_att_dec,
    const float* __restrict__ gvec, const int* __restrict__ hlens,
    const float* __restrict__ b_ih0, const float* __restrict__ b_hh0,
    const float* __restrict__ b_ih1, const float* __restrict__ b_hh1,
    float* __restrict__ h_dec)
{
  cg::grid_group grid = cg::this_grid();
  int bk = blockIdx.x, tid = threadIdx.x;
  int lane = tid & 63, wv = tid >> 6;
  int d0 = bk * 2;

  __shared__ float whh0_s[8*512];   // [gd][k]
  __shared__ float whh1_s[8*512];
  __shared__ float wih1_s[8*512];
  __shared__ float wdec_s[2*512];   // [delta][k]
  __shared__ float hsw_s[4*8*256];  // [b][gd][t(pad 256)]
  __shared__ float pre0_s[480*8];   // [(b*120+u)][gd]
  __shared__ float pre_s[4*512];    // e-rows
  __shared__ float gvec_s[512];
  __shared__ float zs0[2048], zs1[2048], qs[2048];
  __shared__ float pA0[32], pA1[32], gB[32], gC[32];
  __shared__ float bias0_s[8], bias1_s[8], c0_s[8], c1_s[8];
  __shared__ int hlens_s[4];

  // ---- one-time LDS load (coalesced rows from original j-major weights) ----
  for (int idx = tid; idx < 8*512; idx += 256){
    int gd = idx >> 9, k = idx & 511;
    int j = (gd >> 1)*512 + d0 + (gd & 1);
    whh0_s[idx] = W_hh0[(size_t)j*512 + k];
    whh1_s[idx] = W_hh1[(size_t)j*512 + k];
    wih1_s[idx] = W_ih1[(size_t)j*512 + k];
  }
  for (int idx = tid; idx < 2*512; idx += 256){
    int dd = idx >> 9, k = idx & 511;
    wdec_s[idx] = W_att_dec[(size_t)k*512 + d0 + dd];
  }
  for (int idx = tid; idx < 4*1000; idx += 256){
    int gp = idx & 3, tg = idx >> 2;
    int b = tg / 250, t = tg - b*250;
    const float2 v = *(const float2*)(hsW0 + (size_t)tg*G_ + gp*512 + d0);
    hsw_s[(b*8 + gp*2 + 0)*256 + t] = v.x;
    hsw_s[(b*8 + gp*2 + 1)*256 + t] = v.y;
  }
  for (int idx = tid; idx < 4*8*6; idx += 256){   // zero t-pad 250..255
    int t = 250 + (idx % 6), bg = idx / 6;
    hsw_s[bg*256 + t] = 0.f;
  }
  for (int idx = tid; idx < 480*4; idx += 256){
    int gp = idx & 3, r = idx >> 2;
    const float2 v = *(const float2*)(pre0 + (size_t)r*G_ + gp*512 + d0);
    pre0_s[r*8 + gp*2 + 0] = v.x;
    pre0_s[r*8 + gp*2 + 1] = v.y;
  }
  for (int idx = tid; idx < 4*512; idx += 256){
    int r = bk*4 + (idx >> 9);
    pre_s[idx] = (r < B_*T_) ? pre_enc[(size_t)r*512 + (idx & 511)] : 0.f;
  }
  for (int idx = tid; idx < 512; idx += 256) gvec_s[idx] = gvec[idx];
  if (tid < 4) hlens_s[tid] = hlens[tid];
  if (tid < 8){
    int j = ((tid >> 1))*512 + d0 + (tid & 1);   // gd=tid: g=tid>>1, delta=tid&1
    bias0_s[tid] = b_ih0[j] + b_hh0[j];
    bias1_s[tid] = b_ih1[j] + b_hh1[j];
    c0_s[tid] = 0.f; c1_s[tid] = 0.f;
    // init owned global state entries: (b=tid>>1, d=d0+(tid&1))
    int b = tid >> 1, d = d0 + (tid & 1);
    z0[b*512 + d] = 0.f;
    z1[b*512 + d] = 0.f;
    q [b*512 + d] = 0.f;
  }
  __syncthreads();
  grid.sync();

  for (int u = 0; u < U_; ++u){
    // ---------------- Phase A ----------------
    for (int i = tid; i < 2048; i += 256){
      zs0[i] = z0[i]; zs1[i] = z1[i]; qs[i] = q[i];
    }
    __syncthreads();
    {
      int gd0 = wv*2, gd1 = wv*2 + 1;
      float a00[4]={}, a01[4]={}, a10[4]={}, a11[4]={};
#pragma unroll
      for (int i = 0; i < 8; ++i){
        int k = i*64 + lane;
        float w00 = whh0_s[gd0*512+k], w01 = whh0_s[gd1*512+k];
        float w10 = whh1_s[gd0*512+k], w11 = whh1_s[gd1*512+k];
#pragma unroll
        for (int b=0;b<4;b++){
          float zv0 = zs0[b*512+k], zv1 = zs1[b*512+k];
          a00[b] += w00*zv0; a01[b] += w01*zv0;
          a10[b] += w10*zv1; a11[b] += w11*zv1;
        }
      }
#pragma unroll
      for (int b=0;b<4;b++){
#pragma unroll
        for (int off=32; off; off>>=1){
          a00[b] += __shfl_xor(a00[b],off); a01[b] += __shfl_xor(a01[b],off);
          a10[b] += __shfl_xor(a10[b],off); a11[b] += __shfl_xor(a11[b],off);
        }
      }
      if (lane == 0){
#pragma unroll
        for (int b=0;b<4;b++){
          pA0[b*8+gd0] = a00[b]; pA0[b*8+gd1] = a01[b];
          pA1[b*8+gd0] = a10[b]; pA1[b*8+gd1] = a11[b];
        }
      }
    }
    {
      int r = bk*4 + wv;
      if (r < B_*T_){
        int b = r / 250, t = r - b*250;
        float s = 0.f;
#pragma unroll
        for (int i=0;i<8;i++){
          int k = i*64 + lane;
          float x = pre_s[wv*512+k] + qs[b*512+k];
          s += tanh_fast(x) * gvec_s[k];
        }
#pragma unroll
        for (int off=32; off; off>>=1) s += __shfl_xor(s, off);
        if (lane == 0) e[r] = (t < hlens_s[b]) ? s : -1e30f;
      }
    }
    grid.sync();
    // ---------------- Phase B ----------------
    {
      int b = wv;  // wave handles batch wv
      float vals[4], w_reg[4];
      float vmax = -1e30f;
#pragma unroll
      for (int i=0;i<4;i++){
        int t = i*64 + lane;
        vals[i] = (t < 250) ? e[b*250 + t] : -1e30f;
        vmax = fmaxf(vmax, vals[i]);
      }
#pragma unroll
      for (int off=32; off; off>>=1) vmax = fmaxf(vmax, __shfl_xor(vmax, off));
      float ssum = 0.f;
#pragma unroll
      for (int i=0;i<4;i++){
        int t = i*64 + lane;
        w_reg[i] = (t < 250) ? __expf(vals[i] - vmax) : 0.f;
        ssum += w_reg[i];
      }
#pragma unroll
      for (int off=32; off; off>>=1) ssum += __shfl_xor(ssum, off);
      float inv = 1.f / ssum;
#pragma unroll
      for (int i=0;i<4;i++) w_reg[i] *= inv;

      float ag[8] = {};
#pragma unroll
      for (int i=0;i<4;i++){
        int t = i*64 + lane;
#pragma unroll
        for (int gd=0; gd<8; gd++)
          ag[gd] += w_reg[i] * hsw_s[(b*8+gd)*256 + t];
      }
#pragma unroll
      for (int gd=0; gd<8; gd++){
#pragma unroll
        for (int off=32; off; off>>=1) ag[gd] += __shfl_xor(ag[gd], off);
      }
      if (lane == 0){
#pragma unroll
        for (int gd=0; gd<8; gd++)
          gB[b*8+gd] = ag[gd] + pA0[b*8+gd] + pre0_s[(b*U_+u)*8 + gd] + bias0_s[gd];
      }
    }
    __syncthreads();
    if (tid < 8){
      int b = tid >> 1, dd = tid & 1;
      float ig = sigmoid_fast(gB[b*8 + 0 + dd]);
      float fg = sigmoid_fast(gB[b*8 + 2 + dd]);
      float gg = tanh_fast  (gB[b*8 + 4 + dd]);
      float og = sigmoid_fast(gB[b*8 + 6 + dd]);
      float cn = fg * c0_s[tid] + ig * gg;
      c0_s[tid] = cn;
      z0[b*512 + d0 + dd] = og * tanh_fast(cn);
    }
    grid.sync();
    // ---------------- Phase C ----------------
    for (int i = tid; i < 2048; i += 256) zs0[i] = z0[i];
    __syncthreads();
    {
      int gd0 = wv*2, gd1 = wv*2 + 1;
      float a0[4]={}, a1[4]={};
#pragma unroll
      for (int i=0;i<8;i++){
        int k = i*64 + lane;
        float w0 = wih1_s[gd0*512+k], w1 = wih1_s[gd1*512+k];
#pragma unroll
        for (int b=0;b<4;b++){
          float zv = zs0[b*512+k];
          a0[b] += w0*zv; a1[b] += w1*zv;
        }
      }
#pragma unroll
      for (int b=0;b<4;b++){
#pragma unroll
        for (int off=32; off; off>>=1){
          a0[b] += __shfl_xor(a0[b],off); a1[b] += __shfl_xor(a1[b],off);
        }
      }
      if (lane == 0){
#pragma unroll
        for (int b=0;b<4;b++){
          gC[b*8+gd0] = a0[b] + pA1[b*8+gd0] + bias1_s[gd0];
          gC[b*8+gd1] = a1[b] + pA1[b*8+gd1] + bias1_s[gd1];
        }
      }
      if (wv < 2){
        float qa[4] = {};
#pragma unroll
        for (int i=0;i<8;i++){
          int k = i*64 + lane;
          float wq = wdec_s[wv*512+k];
#pragma unroll
          for (int b=0;b<4;b++) qa[b] += wq * zs0[b*512+k];
        }
#pragma unroll
        for (int b=0;b<4;b++){
#pragma unroll
          for (int off=32; off; off>>=1) qa[b] += __shfl_xor(qa[b],off);
        }
        if (lane == 0){
#pragma unroll
          for (int b=0;b<4;b++) q[b*512 + d0 + wv] = qa[b];
        }
      }
    }
    __syncthreads();
    if (tid < 8){
      int b = tid >> 1, dd = tid & 1;
      float ig = sigmoid_fast(gC[b*8 + 0 + dd]);
      float fg = sigmoid_fast(gC[b*8 + 2 + dd]);
      float gg = tanh_fast  (gC[b*8 + 4 + dd]);
      float og = sigmoid_fast(gC[b*8 + 6 + dd]);
      float cn = fg * c1_s[tid] + ig * gg;
      c1_s[tid] = cn;
      float hn = og * tanh_fast(cn);
      z1[b*512 + d0 + dd] = hn;
      h_dec[((size_t)(b*U_ + u))*512 + d0 + dd] = hn;
    }
    grid.sync();
  }
}

// ---------- fallback f32 joint ----------
#define JKC 16
__global__ __launch_bounds__(256) void joint_k(
    const float* __restrict__ henc, const float* __restrict__ hdec,
    const float* __restrict__ Wout, const float* __restrict__ bout,
    float* __restrict__ out)
{
  int ot = blockIdx.x;
  int t  = blockIdx.y;
  int b  = blockIdx.z;
  __shared__ float As[128][JKC+1];
  __shared__ float Bs[128][JKC+1];
  int tid = threadIdx.x;
  int tx = tid & 15, ty = tid >> 4;
  float acc[8][8] = {};
  const float* henc_row = henc + (size_t)(b*T_ + t)*512;
  for (int k0 = 0; k0 < 512; k0 += JKC){
#pragma unroll
    for (int i=0;i<8;i++){
      int e = tid*8+i; int r = e>>4, kk = e&15;
      float hv = henc_row[k0+kk];
      float dv = (r < U_) ? hdec[(size_t)(b*U_ + r)*512 + k0 + kk] : 0.f;
      As[r][kk] = tanh_fast(hv+dv);
      Bs[r][kk] = Wout[(size_t)(ot*128 + r)*512 + k0 + kk];
    }
    __syncthreads();
#pragma unroll
    for (int kk=0; kk<JKC; kk++){
      float a[8], bb[8];
#pragma unroll
      for (int i=0;i<8;i++) a[i]  = As[ty*8+i][kk];
#pragma unroll
      for (int j=0;j<8;j++) bb[j] = Bs[tx*8+j][kk];
#pragma unroll
      for (int i=0;i<8;i++)
#pragma unroll
        for (int j=0;j<8;j++)
          acc[i][j] += a[i]*bb[j];
    }
    __syncthreads();
  }
  int o0 = ot*128 + tx*8;
#pragma unroll
  for (int i=0;i<8;i++){
    int u = ty*8 + i;
    if (u < U_){
      float* op = out + ((size_t)(b*T_ + t)*U_ + u)*O_ + o0;
#pragma unroll
      for (int j=0;j<8;j++) op[j] = acc[i][j] + bout[o0+j];
    }
  }
}

// ---------- bf16 MFMA joint path ----------
__global__ __launch_bounds__(256) void tanh_pack_k(
    const float* __restrict__ henc, const float* __restrict__ hdec,
    unsigned short* __restrict__ P)
{
  int i = blockIdx.x*256 + threadIdx.x;
  if (i >= B_*T_*U_*512/8) return;
  int e = i*8;
  int k = e & 511;
  int r = e >> 9;
  int u = r % U_;
  int bt = r / U_;
  int b = bt / T_;
  const float* hp = henc + (size_t)bt*512 + k;
  const float* dp = hdec + (size_t)(b*U_ + u)*512 + k;
  unsigned int w[4];
#pragma unroll
  for (int j=0;j<4;j++){
    unsigned short lo = f2bf(tanh_fast(hp[2*j]   + dp[2*j]));
    unsigned short hi = f2bf(tanh_fast(hp[2*j+1] + dp[2*j+1]));
    w[j] = (unsigned int)lo | ((unsigned int)hi << 16);
  }
  ui4* dst = (ui4*)(P + e);
  *dst = ui4{w[0], w[1], w[2], w[3]};
}

__global__ __launch_bounds__(256) void wconv_k(const float* __restrict__ W,
                                               unsigned short* __restrict__ Wb, int n8){
  int i = blockIdx.x*256 + threadIdx.x;
  if (i >= n8) return;
  int e = i*8;
  unsigned int w[4];
#pragma unroll
  for (int j=0;j<4;j++){
    unsigned short lo = f2bf(W[e+2*j]);
    unsigned short hi = f2bf(W[e+2*j+1]);
    w[j] = (unsigned int)lo | ((unsigned int)hi << 16);
  }
  *(ui4*)(Wb + e) = ui4{w[0], w[1], w[2], w[3]};
}

__global__ __launch_bounds__(256) void joint_mfma_k(
    const unsigned short* __restrict__ P,
    const unsigned short* __restrict__ Wb,
    const float* __restrict__ bout,
    float* __restrict__ out)
{
  __shared__ unsigned short As[128*64];
  __shared__ unsigned short Bs[128*64];
  int tid = threadIdx.x;
  int lane = tid & 63;
  int w = tid >> 6, wr = w >> 1, wc = w & 1;
  int o0 = blockIdx.x * 128;
  int t = blockIdx.y, b = blockIdx.z;
  int bt = b*T_ + t;
  const char* Pbase = (const char*)(P + (size_t)bt*U_*512);
  const char* Wbase = (const char*)(Wb + (size_t)o0*512);

  f32x4 acc[4][4] = {};

  for (int k0 = 0; k0 < 512; k0 += 64){
    __syncthreads();
#pragma unroll
    for (int j=0;j<4;j++){
      int pos = (j*256 + tid)*16;
      int row = pos >> 7;
      int inrow = pos & 127;
      int srcin = inrow ^ ((row & 7) << 4);
      int arow = row < U_ ? row : (U_-1);
      __builtin_amdgcn_global_load_lds(
        (const __attribute__((address_space(1))) void*)(Pbase + (size_t)arow*1024 + k0*2 + srcin),
        (__attribute__((address_space(3))) void*)((char*)As + pos), 16, 0, 0);
      __builtin_amdgcn_global_load_lds(
        (const __attribute__((address_space(1))) void*)(Wbase + (size_t)row*1024 + k0*2 + srcin),
        (__attribute__((address_space(3))) void*)((char*)Bs + pos), 16, 0, 0);
    }
    __syncthreads();
#pragma unroll
    for (int kk=0; kk<2; kk++){
      bf16x8 a[4], bb[4];
#pragma unroll
      for (int m=0;m<4;m++){
        int row = wr*64 + m*16 + (lane & 15);
        int inrow = (kk*64 + (lane >> 4)*16) ^ ((row & 7) << 4);
        a[m] = *(const bf16x8*)((const char*)As + row*128 + inrow);
      }
#pragma unroll
      for (int n=0;n<4;n++){
        int row = wc*64 + n*16 + (lane & 15);
        int inrow = (kk*64 + (lane >> 4)*16) ^ ((row & 7) << 4);
        bb[n] = *(const bf16x8*)((const char*)Bs + row*128 + inrow);
      }
#pragma unroll
      for (int m=0;m<4;m++)
#pragma unroll
        for (int n=0;n<4;n++)
          acc[m][n] = __builtin_amdgcn_mfma_f32_16x16x32_bf16(a[m], bb[n], acc[m][n], 0, 0, 0);
    }
  }
#pragma unroll
  for (int n=0;n<4;n++){
    int o = o0 + wc*64 + n*16 + (lane & 15);
    float bias = bout[o];
#pragma unroll
    for (int m=0;m<4;m++){
      int ubase = wr*64 + m*16 + ((lane >> 4) << 2);
#pragma unroll
      for (int r=0;r<4;r++){
        int u = ubase + r;
        if (u < U_)
          out[((size_t)bt*U_ + u)*O_ + o] = acc[m][n][r] + bias;
      }
    }
  }
}

extern "C" void kernel_launch(void* const* d_in, const int* in_sizes, int n_in,
                              void* d_out, int out_size, void* d_ws, size_t ws_size,
                              hipStream_t stream) {
  const float* hs       = (const float*)d_in[0];
  const int*   ys       = (const int*)  d_in[1];
  const int*   hlens    = (const int*)  d_in[2];
  const float* embed    = (const float*)d_in[3];
  const float* W_ih0    = (const float*)d_in[4];
  const float* b_ih0    = (const float*)d_in[5];
  const float* W_hh0    = (const float*)d_in[6];
  const float* b_hh0    = (const float*)d_in[7];
  const float* W_ih1    = (const float*)d_in[8];
  const float* b_ih1    = (const float*)d_in[9];
  const float* W_hh1    = (const float*)d_in[10];
  const float* b_hh1    = (const float*)d_in[11];
  const float* W_att_enc= (const float*)d_in[12];
  const float* b_att_enc= (const float*)d_in[13];
  const float* W_att_dec= (const float*)d_in[14];
  const float* gvec     = (const float*)d_in[15];
  const float* W_lin_enc= (const float*)d_in[16];
  const float* b_lin_enc= (const float*)d_in[17];
  const float* W_lin_dec= (const float*)d_in[18];
  const float* W_lin_out= (const float*)d_in[19];
  const float* b_lin_out= (const float*)d_in[20];
  float* out = (float*)d_out;

  float* w = (float*)d_ws;
  // ws layout (float offsets)
  float* z0      = w;              // 2048
  float* z1      = w + 2048;       // 2048
  float* q       = w + 4096;       // 2048
  float* e       = w + 6144;       // 1024
  float* eys     = w + 7168;       // 245760
  float* pre_enc = w + 252928;     // 512000
  float* pre0    = w + 764928;     // 983040
  float* henc    = w + 1747968;    // 512000
  float* h_dec   = w + 2259968;    // 245760
  float* hdec_p  = w + 2505728;    // 245760
  float* hsW0    = w + 2751488;    // 2048000 -> 4799488
  unsigned short* Pbf = (unsigned short*)(w + 4799488);            // 61,440,000 bf16
  unsigned short* Wbf = (unsigned short*)(w + 4799488 + 30720000); // 524,288 bf16
  const size_t ws_needed = (size_t)(4799488 + 30720000 + 262144) * 4;

  gather_embed_k<<<(B_*U_*D_ + 255)/256, 256, 0, stream>>>(ys, embed, eys);
  // pre_enc = hs @ W_att_enc + b (nn)
  gemm64_nn_k<<<dim3(8, 16), 256, 0, stream>>>(hs, 512, W_att_enc, 512, b_att_enc,
                                               pre_enc, 512, B_*T_, 512, 512);
  // pre0 = eys @ W_ih0[:, :512]^T
  gemm64_nt_k<<<dim3(32, 8), 256, 0, stream>>>(eys, 512, W_ih0, 1024, nullptr,
                                               pre0, 2048, B_*U_, 2048, 512);
  // hsW0 = hs @ W_ih0[:, 512:]^T
  gemm64_nt_k<<<dim3(32, 16), 256, 0, stream>>>(hs, 512, W_ih0 + 512, 1024, nullptr,
                                                hsW0, 2048, B_*T_, 2048, 512);
  // henc = hs @ W_lin_enc^T + b
  gemm64_nt_k<<<dim3(8, 16), 256, 0, stream>>>(hs, 512, W_lin_enc, 512, b_lin_enc,
                                               henc, 512, B_*T_, 512, 512);

  // cooperative LDS-resident scan
  {
    void* args[] = {
      (void*)&z0, (void*)&z1, (void*)&q, (void*)&e,
      (void*)&pre_enc, (void*)&pre0, (void*)&hsW0,
      (void*)&W_hh0, (void*)&W_ih1, (void*)&W_hh1, (void*)&W_att_dec,
      (void*)&gvec, (void*)&hlens,
      (void*)&b_ih0, (void*)&b_hh0, (void*)&b_ih1, (void*)&b_hh1,
      (void*)&h_dec
    };
    hipLaunchCooperativeKernel((const void*)scan_k, dim3(256), dim3(256),
                               args, 0, stream);
  }

  // hdec = h_dec @ W_lin_dec^T
  gemm64_nt_k<<<dim3(8, 8), 256, 0, stream>>>(h_dec, 512, W_lin_dec, 512, nullptr,
                                              hdec_p, 512, B_*U_, 512, 512);
  if (ws_size >= ws_needed){
    tanh_pack_k<<<(B_*T_*U_*512/8 + 255)/256, 256, 0, stream>>>(henc, hdec_p, Pbf);
    wconv_k<<<(O_*512/8 + 255)/256, 256, 0, stream>>>(W_lin_out, Wbf, O_*512/8);
    joint_mfma_k<<<dim3(8, T_, B_), 256, 0, stream>>>(Pbf, Wbf, b_lin_out, out);
  } else {
    joint_k<<<dim3(8, T_, B_), 256, 0, stream>>>(henc, hdec_p, W_lin_out, b_lin_out, out);
  }
}

// Round 5
// 4146.054 us; speedup vs baseline: 3.3731x; 2.8473x over previous
//
#include <hip/hip_runtime.h>

#define B_ 4
#define T_ 250
#define U_ 120
#define D_ 512
#define G_ 2048   // 4*D (gates)
#define O_ 1024   // odim
#define NBLK 256

typedef __attribute__((ext_vector_type(8))) short bf16x8;
typedef __attribute__((ext_vector_type(4))) float f32x4;
typedef __attribute__((ext_vector_type(4))) unsigned int ui4;

__device__ __forceinline__ float tanh_fast(float x){
  float e = __expf(2.f*x);
  return 1.f - 2.f/(e + 1.f);
}
__device__ __forceinline__ float sigmoid_fast(float x){
  return 1.f/(1.f + __expf(-x));
}
__device__ __forceinline__ unsigned short f2bf(float x){
  unsigned int u = __float_as_uint(x);
  unsigned int r = (u + 0x7FFFu + ((u >> 16) & 1u)) >> 16;
  return (unsigned short)r;
}

// MALL-coherent data exchange (sc0 sc1 loads/stores, no cache flush)
__device__ __forceinline__ float atomLoadF(const float* p){
  return __hip_atomic_load(p, __ATOMIC_RELAXED, __HIP_MEMORY_SCOPE_AGENT);
}
__device__ __forceinline__ void atomStoreF(float* p, float v){
  __hip_atomic_store(p, v, __ATOMIC_RELAXED, __HIP_MEMORY_SCOPE_AGENT);
}

// monotonic-counter grid barrier: bar[0]=cnt, bar[1]=gen
__device__ __forceinline__ void gbar(int* bar, int target){
  __syncthreads();   // drains vmcnt(0) for every wave before s_barrier
  if (threadIdx.x == 0){
    asm volatile("s_waitcnt vmcnt(0)" ::: "memory");
    int prev = __hip_atomic_fetch_add(&bar[0], 1, __ATOMIC_RELAXED,
                                      __HIP_MEMORY_SCOPE_AGENT);
    if (prev == target*NBLK - 1){
      __hip_atomic_store(&bar[1], target, __ATOMIC_RELAXED,
                         __HIP_MEMORY_SCOPE_AGENT);
    } else {
      long c = 0;
      while (__hip_atomic_load(&bar[1], __ATOMIC_RELAXED,
                               __HIP_MEMORY_SCOPE_AGENT) < target){
        if (++c > (1L<<24)) break;   // anti-hang valve
      }
    }
    asm volatile("" ::: "memory");
  }
  __syncthreads();
}

__global__ void barinit_k(int* bar){
  if (threadIdx.x < 2)
    __hip_atomic_store(&bar[threadIdx.x], 0, __ATOMIC_RELAXED,
                       __HIP_MEMORY_SCOPE_AGENT);
}

__global__ void gather_embed_k(const int* __restrict__ ys, const float* __restrict__ embed,
                               float* __restrict__ eys){
  int i = blockIdx.x*256 + threadIdx.x;
  if (i < B_*U_*D_){
    int r = i >> 9, k = i & 511;
    eys[i] = embed[ys[r]*D_ + k];
  }
}

// ---------- 64x64-tile f32 GEMMs for precompute ----------
__global__ __launch_bounds__(256) void gemm64_nt_k(
  const float* __restrict__ A, int lda, const float* __restrict__ B, int ldb,
  const float* __restrict__ bias, float* __restrict__ C, int ldc,
  int M, int N, int K)
{
  __shared__ float As[16][65], Bs[16][65];
  int tid = threadIdx.x;
  int m0 = blockIdx.y*64, n0 = blockIdx.x*64;
  int tx = tid & 15, ty = tid >> 4;
  float acc[4][4] = {};
  for (int k0 = 0; k0 < K; k0 += 16){
#pragma unroll
    for (int i=0;i<4;i++){
      int e = tid + 256*i;
      int mm = e >> 4, kk = e & 15;
      int mg = m0 + mm;
      As[kk][mm] = (mg < M) ? A[(size_t)mg*lda + k0 + kk] : 0.f;
      int ng = n0 + mm;
      Bs[kk][mm] = (ng < N) ? B[(size_t)ng*ldb + k0 + kk] : 0.f;
    }
    __syncthreads();
#pragma unroll
    for (int kk=0;kk<16;kk++){
      float av[4], bv[4];
#pragma unroll
      for (int i=0;i<4;i++) av[i] = As[kk][ty*4+i];
#pragma unroll
      for (int j=0;j<4;j++) bv[j] = Bs[kk][tx*4+j];
#pragma unroll
      for (int i=0;i<4;i++)
#pragma unroll
        for (int j=0;j<4;j++) acc[i][j] += av[i]*bv[j];
    }
    __syncthreads();
  }
#pragma unroll
  for (int i=0;i<4;i++){
    int m = m0 + ty*4 + i;
    if (m < M){
#pragma unroll
      for (int j=0;j<4;j++){
        int n = n0 + tx*4 + j;
        if (n < N) C[(size_t)m*ldc + n] = acc[i][j] + (bias ? bias[n] : 0.f);
      }
    }
  }
}

__global__ __launch_bounds__(256) void gemm64_nn_k(
  const float* __restrict__ A, int lda, const float* __restrict__ B, int ldb,
  const float* __restrict__ bias, float* __restrict__ C, int ldc,
  int M, int N, int K)
{
  __shared__ float As[16][65], Bs[16][65];
  int tid = threadIdx.x;
  int m0 = blockIdx.y*64, n0 = blockIdx.x*64;
  int tx = tid & 15, ty = tid >> 4;
  float acc[4][4] = {};
  for (int k0 = 0; k0 < K; k0 += 16){
#pragma unroll
    for (int i=0;i<4;i++){
      int e = tid + 256*i;
      int mm = e >> 4, kk = e & 15;
      int mg = m0 + mm;
      As[kk][mm] = (mg < M) ? A[(size_t)mg*lda + k0 + kk] : 0.f;
      int nn = e & 63, kk2 = e >> 6;
      int ng = n0 + nn;
      Bs[kk2][nn] = (ng < N) ? B[(size_t)(k0+kk2)*ldb + ng] : 0.f;
    }
    __syncthreads();
#pragma unroll
    for (int kk=0;kk<16;kk++){
      float av[4], bv[4];
#pragma unroll
      for (int i=0;i<4;i++) av[i] = As[kk][ty*4+i];
#pragma unroll
      for (int j=0;j<4;j++) bv[j] = Bs[kk][tx*4+j];
#pragma unroll
      for (int i=0;i<4;i++)
#pragma unroll
        for (int j=0;j<4;j++) acc[i][j] += av[i]*bv[j];
    }
    __syncthreads();
  }
#pragma unroll
  for (int i=0;i<4;i++){
    int m = m0 + ty*4 + i;
    if (m < M){
#pragma unroll
      for (int j=0;j<4;j++){
        int n = n0 + tx*4 + j;
        if (n < N) C[(size_t)m*ldc + n] = acc[i][j] + (bias ? bias[n] : 0.f);
      }
    }
  }
}

// ---------- LDS-resident scan with hand-rolled MALL barrier ----------
// 256 blocks x 256 threads. Block bk owns d = {2bk, 2bk+1}. All weights in LDS.
__global__ __launch_bounds__(256) void scan_k(
    float* __restrict__ z0, float* __restrict__ z1,
    float* __restrict__ q,  float* __restrict__ e, int* __restrict__ bar,
    const float* __restrict__ pre_enc, const float* __restrict__ pre0,
    const float* __restrict__ hsW0,
    const float* __restrict__ W_hh0, const float* __restrict__ W_ih1,
    const float* __restrict__ W_hh1, const float* __restrict__ W_att_dec,
    const float* __restrict__ gvec, const int* __restrict__ hlens,
    const float* __restrict__ b_ih0, const float* __restrict__ b_hh0,
    const float* __restrict__ b_ih1, const float* __restrict__ b_hh1,
    float* __restrict__ h_dec)
{
  int bk = blockIdx.x, tid = threadIdx.x;
  int lane = tid & 63, wv = tid >> 6;
  int d0 = bk * 2;

  __shared__ float whh0_s[8*512];   // [gd][k]
  __shared__ float whh1_s[8*512];
  __shared__ float wih1_s[8*512];
  __shared__ float wdec_s[2*512];   // [delta][k]
  __shared__ float hsw_s[4*8*256];  // [b][gd][t(pad 256)]
  __shared__ float pre0_s[480*8];   // [(b*120+u)][gd]
  __shared__ float pre_s[4*512];    // e-rows
  __shared__ float gvec_s[512];
  __shared__ float zs0[2048], zs1[2048], qs[2048];
  __shared__ float pA0[32], pA1[32], gB[32], gC[32];
  __shared__ float bias0_s[8], bias1_s[8], c0_s[8], c1_s[8];
  __shared__ int hlens_s[4];

  // ---- one-time LDS load (coalesced rows from original j-major weights) ----
  for (int idx = tid; idx < 8*512; idx += 256){
    int gd = idx >> 9, k = idx & 511;
    int j = (gd >> 1)*512 + d0 + (gd & 1);
    whh0_s[idx] = W_hh0[(size_t)j*512 + k];
    whh1_s[idx] = W_hh1[(size_t)j*512 + k];
    wih1_s[idx] = W_ih1[(size_t)j*512 + k];
  }
  for (int idx = tid; idx < 2*512; idx += 256){
    int dd = idx >> 9, k = idx & 511;
    wdec_s[idx] = W_att_dec[(size_t)k*512 + d0 + dd];
  }
  for (int idx = tid; idx < 4*1000; idx += 256){
    int gp = idx & 3, tg = idx >> 2;
    int b = tg / 250, t = tg - b*250;
    const float2 v = *(const float2*)(hsW0 + (size_t)tg*G_ + gp*512 + d0);
    hsw_s[(b*8 + gp*2 + 0)*256 + t] = v.x;
    hsw_s[(b*8 + gp*2 + 1)*256 + t] = v.y;
  }
  for (int idx = tid; idx < 4*8*6; idx += 256){   // zero t-pad 250..255
    int t = 250 + (idx % 6), bg = idx / 6;
    hsw_s[bg*256 + t] = 0.f;
  }
  for (int idx = tid; idx < 480*4; idx += 256){
    int gp = idx & 3, r = idx >> 2;
    const float2 v = *(const float2*)(pre0 + (size_t)r*G_ + gp*512 + d0);
    pre0_s[r*8 + gp*2 + 0] = v.x;
    pre0_s[r*8 + gp*2 + 1] = v.y;
  }
  for (int idx = tid; idx < 4*512; idx += 256){
    int r = bk*4 + (idx >> 9);
    pre_s[idx] = (r < B_*T_) ? pre_enc[(size_t)r*512 + (idx & 511)] : 0.f;
  }
  for (int idx = tid; idx < 512; idx += 256) gvec_s[idx] = gvec[idx];
  if (tid < 4) hlens_s[tid] = hlens[tid];
  if (tid < 8){
    int j = ((tid >> 1))*512 + d0 + (tid & 1);
    bias0_s[tid] = b_ih0[j] + b_hh0[j];
    bias1_s[tid] = b_ih1[j] + b_hh1[j];
    c0_s[tid] = 0.f; c1_s[tid] = 0.f;
    int b = tid >> 1, d = d0 + (tid & 1);
    atomStoreF(&z0[b*512 + d], 0.f);
    atomStoreF(&z1[b*512 + d], 0.f);
    atomStoreF(&q [b*512 + d], 0.f);
  }
  int gen = 0;
  gbar(bar, ++gen);

  for (int u = 0; u < U_; ++u){
    // ---------------- Phase A ----------------
    for (int i = tid; i < 2048; i += 256){
      zs0[i] = atomLoadF(&z0[i]);
      zs1[i] = atomLoadF(&z1[i]);
      qs[i]  = atomLoadF(&q[i]);
    }
    __syncthreads();
    {
      int gd0 = wv*2, gd1 = wv*2 + 1;
      float a00[4]={}, a01[4]={}, a10[4]={}, a11[4]={};
#pragma unroll
      for (int i = 0; i < 8; ++i){
        int k = i*64 + lane;
        float w00 = whh0_s[gd0*512+k], w01 = whh0_s[gd1*512+k];
        float w10 = whh1_s[gd0*512+k], w11 = whh1_s[gd1*512+k];
#pragma unroll
        for (int b=0;b<4;b++){
          float zv0 = zs0[b*512+k], zv1 = zs1[b*512+k];
          a00[b] += w00*zv0; a01[b] += w01*zv0;
          a10[b] += w10*zv1; a11[b] += w11*zv1;
        }
      }
#pragma unroll
      for (int b=0;b<4;b++){
#pragma unroll
        for (int off=32; off; off>>=1){
          a00[b] += __shfl_xor(a00[b],off); a01[b] += __shfl_xor(a01[b],off);
          a10[b] += __shfl_xor(a10[b],off); a11[b] += __shfl_xor(a11[b],off);
        }
      }
      if (lane == 0){
#pragma unroll
        for (int b=0;b<4;b++){
          pA0[b*8+gd0] = a00[b]; pA0[b*8+gd1] = a01[b];
          pA1[b*8+gd0] = a10[b]; pA1[b*8+gd1] = a11[b];
        }
      }
    }
    {
      int r = bk*4 + wv;
      if (r < B_*T_){
        int b = r / 250, t = r - b*250;
        float s = 0.f;
#pragma unroll
        for (int i=0;i<8;i++){
          int k = i*64 + lane;
          float x = pre_s[wv*512+k] + qs[b*512+k];
          s += tanh_fast(x) * gvec_s[k];
        }
#pragma unroll
        for (int off=32; off; off>>=1) s += __shfl_xor(s, off);
        if (lane == 0) atomStoreF(&e[r], (t < hlens_s[b]) ? s : -1e30f);
      }
    }
    gbar(bar, ++gen);
    // ---------------- Phase B ----------------
    {
      int b = wv;  // wave handles batch wv
      float vals[4], w_reg[4];
      float vmax = -1e30f;
#pragma unroll
      for (int i=0;i<4;i++){
        int t = i*64 + lane;
        vals[i] = (t < 250) ? atomLoadF(&e[b*250 + t]) : -1e30f;
        vmax = fmaxf(vmax, vals[i]);
      }
#pragma unroll
      for (int off=32; off; off>>=1) vmax = fmaxf(vmax, __shfl_xor(vmax, off));
      float ssum = 0.f;
#pragma unroll
      for (int i=0;i<4;i++){
        int t = i*64 + lane;
        w_reg[i] = (t < 250) ? __expf(vals[i] - vmax) : 0.f;
        ssum += w_reg[i];
      }
#pragma unroll
      for (int off=32; off; off>>=1) ssum += __shfl_xor(ssum, off);
      float inv = 1.f / ssum;
#pragma unroll
      for (int i=0;i<4;i++) w_reg[i] *= inv;

      float ag[8] = {};
#pragma unroll
      for (int i=0;i<4;i++){
        int t = i*64 + lane;
#pragma unroll
        for (int gd=0; gd<8; gd++)
          ag[gd] += w_reg[i] * hsw_s[(b*8+gd)*256 + t];
      }
#pragma unroll
      for (int gd=0; gd<8; gd++){
#pragma unroll
        for (int off=32; off; off>>=1) ag[gd] += __shfl_xor(ag[gd], off);
      }
      if (lane == 0){
#pragma unroll
        for (int gd=0; gd<8; gd++)
          gB[b*8+gd] = ag[gd] + pA0[b*8+gd] + pre0_s[(b*U_+u)*8 + gd] + bias0_s[gd];
      }
    }
    __syncthreads();
    if (tid < 8){
      int b = tid >> 1, dd = tid & 1;
      float ig = sigmoid_fast(gB[b*8 + 0 + dd]);
      float fg = sigmoid_fast(gB[b*8 + 2 + dd]);
      float gg = tanh_fast  (gB[b*8 + 4 + dd]);
      float og = sigmoid_fast(gB[b*8 + 6 + dd]);
      float cn = fg * c0_s[tid] + ig * gg;
      c0_s[tid] = cn;
      atomStoreF(&z0[b*512 + d0 + dd], og * tanh_fast(cn));
    }
    gbar(bar, ++gen);
    // ---------------- Phase C ----------------
    for (int i = tid; i < 2048; i += 256) zs0[i] = atomLoadF(&z0[i]);
    __syncthreads();
    {
      int gd0 = wv*2, gd1 = wv*2 + 1;
      float a0[4]={}, a1[4]={};
#pragma unroll
      for (int i=0;i<8;i++){
        int k = i*64 + lane;
        float w0 = wih1_s[gd0*512+k], w1 = wih1_s[gd1*512+k];
#pragma unroll
        for (int b=0;b<4;b++){
          float zv = zs0[b*512+k];
          a0[b] += w0*zv; a1[b] += w1*zv;
        }
      }
#pragma unroll
      for (int b=0;b<4;b++){
#pragma unroll
        for (int off=32; off; off>>=1){
          a0[b] += __shfl_xor(a0[b],off); a1[b] += __shfl_xor(a1[b],off);
        }
      }
      if (lane == 0){
#pragma unroll
        for (int b=0;b<4;b++){
          gC[b*8+gd0] = a0[b] + pA1[b*8+gd0] + bias1_s[gd0];
          gC[b*8+gd1] = a1[b] + pA1[b*8+gd1] + bias1_s[gd1];
        }
      }
      if (wv < 2){
        float qa[4] = {};
#pragma unroll
        for (int i=0;i<8;i++){
          int k = i*64 + lane;
          float wq = wdec_s[wv*512+k];
#pragma unroll
          for (int b=0;b<4;b++) qa[b] += wq * zs0[b*512+k];
        }
#pragma unroll
        for (int b=0;b<4;b++){
#pragma unroll
          for (int off=32; off; off>>=1) qa[b] += __shfl_xor(qa[b],off);
        }
        if (lane == 0){
#pragma unroll
          for (int b=0;b<4;b++) atomStoreF(&q[b*512 + d0 + wv], qa[b]);
        }
      }
    }
    __syncthreads();
    if (tid < 8){
      int b = tid >> 1, dd = tid & 1;
      float ig = sigmoid_fast(gC[b*8 + 0 + dd]);
      float fg = sigmoid_fast(gC[b*8 + 2 + dd]);
      float gg = tanh_fast  (gC[b*8 + 4 + dd]);
      float og = sigmoid_fast(gC[b*8 + 6 + dd]);
      float cn = fg * c1_s[tid] + ig * gg;
      c1_s[tid] = cn;
      float hn = og * tanh_fast(cn);
      atomStoreF(&z1[b*512 + d0 + dd], hn);
      h_dec[((size_t)(b*U_ + u))*512 + d0 + dd] = hn;   // ordinary; read post-kernel
    }
    gbar(bar, ++gen);
  }
}

// ---------- fallback f32 joint ----------
#define JKC 16
__global__ __launch_bounds__(256) void joint_k(
    const float* __restrict__ henc, const float* __restrict__ hdec,
    const float* __restrict__ Wout, const float* __restrict__ bout,
    float* __restrict__ out)
{
  int ot = blockIdx.x;
  int t  = blockIdx.y;
  int b  = blockIdx.z;
  __shared__ float As[128][JKC+1];
  __shared__ float Bs[128][JKC+1];
  int tid = threadIdx.x;
  int tx = tid & 15, ty = tid >> 4;
  float acc[8][8] = {};
  const float* henc_row = henc + (size_t)(b*T_ + t)*512;
  for (int k0 = 0; k0 < 512; k0 += JKC){
#pragma unroll
    for (int i=0;i<8;i++){
      int e = tid*8+i; int r = e>>4, kk = e&15;
      float hv = henc_row[k0+kk];
      float dv = (r < U_) ? hdec[(size_t)(b*U_ + r)*512 + k0 + kk] : 0.f;
      As[r][kk] = tanh_fast(hv+dv);
      Bs[r][kk] = Wout[(size_t)(ot*128 + r)*512 + k0 + kk];
    }
    __syncthreads();
#pragma unroll
    for (int kk=0; kk<JKC; kk++){
      float a[8], bb[8];
#pragma unroll
      for (int i=0;i<8;i++) a[i]  = As[ty*8+i][kk];
#pragma unroll
      for (int j=0;j<8;j++) bb[j] = Bs[tx*8+j][kk];
#pragma unroll
      for (int i=0;i<8;i++)
#pragma unroll
        for (int j=0;j<8;j++)
          acc[i][j] += a[i]*bb[j];
    }
    __syncthreads();
  }
  int o0 = ot*128 + tx*8;
#pragma unroll
  for (int i=0;i<8;i++){
    int u = ty*8 + i;
    if (u < U_){
      float* op = out + ((size_t)(b*T_ + t)*U_ + u)*O_ + o0;
#pragma unroll
      for (int j=0;j<8;j++) op[j] = acc[i][j] + bout[o0+j];
    }
  }
}

// ---------- bf16 MFMA joint path ----------
__global__ __launch_bounds__(256) void tanh_pack_k(
    const float* __restrict__ henc, const float* __restrict__ hdec,
    unsigned short* __restrict__ P)
{
  int i = blockIdx.x*256 + threadIdx.x;
  if (i >= B_*T_*U_*512/8) return;
  int e = i*8;
  int k = e & 511;
  int r = e >> 9;
  int u = r % U_;
  int bt = r / U_;
  int b = bt / T_;
  const float* hp = henc + (size_t)bt*512 + k;
  const float* dp = hdec + (size_t)(b*U_ + u)*512 + k;
  unsigned int w[4];
#pragma unroll
  for (int j=0;j<4;j++){
    unsigned short lo = f2bf(tanh_fast(hp[2*j]   + dp[2*j]));
    unsigned short hi = f2bf(tanh_fast(hp[2*j+1] + dp[2*j+1]));
    w[j] = (unsigned int)lo | ((unsigned int)hi << 16);
  }
  ui4* dst = (ui4*)(P + e);
  *dst = ui4{w[0], w[1], w[2], w[3]};
}

__global__ __launch_bounds__(256) void wconv_k(const float* __restrict__ W,
                                               unsigned short* __restrict__ Wb, int n8){
  int i = blockIdx.x*256 + threadIdx.x;
  if (i >= n8) return;
  int e = i*8;
  unsigned int w[4];
#pragma unroll
  for (int j=0;j<4;j++){
    unsigned short lo = f2bf(W[e+2*j]);
    unsigned short hi = f2bf(W[e+2*j+1]);
    w[j] = (unsigned int)lo | ((unsigned int)hi << 16);
  }
  *(ui4*)(Wb + e) = ui4{w[0], w[1], w[2], w[3]};
}

__global__ __launch_bounds__(256) void joint_mfma_k(
    const unsigned short* __restrict__ P,
    const unsigned short* __restrict__ Wb,
    const float* __restrict__ bout,
    float* __restrict__ out)
{
  __shared__ unsigned short As[128*64];
  __shared__ unsigned short Bs[128*64];
  int tid = threadIdx.x;
  int lane = tid & 63;
  int w = tid >> 6, wr = w >> 1, wc = w & 1;
  int o0 = blockIdx.x * 128;
  int t = blockIdx.y, b = blockIdx.z;
  int bt = b*T_ + t;
  const char* Pbase = (const char*)(P + (size_t)bt*U_*512);
  const char* Wbase = (const char*)(Wb + (size_t)o0*512);

  f32x4 acc[4][4] = {};

  for (int k0 = 0; k0 < 512; k0 += 64){
    __syncthreads();
#pragma unroll
    for (int j=0;j<4;j++){
      int pos = (j*256 + tid)*16;
      int row = pos >> 7;
      int inrow = pos & 127;
      int srcin = inrow ^ ((row & 7) << 4);
      int arow = row < U_ ? row : (U_-1);
      __builtin_amdgcn_global_load_lds(
        (const __attribute__((address_space(1))) void*)(Pbase + (size_t)arow*1024 + k0*2 + srcin),
        (__attribute__((address_space(3))) void*)((char*)As + pos), 16, 0, 0);
      __builtin_amdgcn_global_load_lds(
        (const __attribute__((address_space(1))) void*)(Wbase + (size_t)row*1024 + k0*2 + srcin),
        (__attribute__((address_space(3))) void*)((char*)Bs + pos), 16, 0, 0);
    }
    __syncthreads();
#pragma unroll
    for (int kk=0; kk<2; kk++){
      bf16x8 a[4], bb[4];
#pragma unroll
      for (int m=0;m<4;m++){
        int row = wr*64 + m*16 + (lane & 15);
        int inrow = (kk*64 + (lane >> 4)*16) ^ ((row & 7) << 4);
        a[m] = *(const bf16x8*)((const char*)As + row*128 + inrow);
      }
#pragma unroll
      for (int n=0;n<4;n++){
        int row = wc*64 + n*16 + (lane & 15);
        int inrow = (kk*64 + (lane >> 4)*16) ^ ((row & 7) << 4);
        bb[n] = *(const bf16x8*)((const char*)Bs + row*128 + inrow);
      }
#pragma unroll
      for (int m=0;m<4;m++)
#pragma unroll
        for (int n=0;n<4;n++)
          acc[m][n] = __builtin_amdgcn_mfma_f32_16x16x32_bf16(a[m], bb[n], acc[m][n], 0, 0, 0);
    }
  }
#pragma unroll
  for (int n=0;n<4;n++){
    int o = o0 + wc*64 + n*16 + (lane & 15);
    float bias = bout[o];
#pragma unroll
    for (int m=0;m<4;m++){
      int ubase = wr*64 + m*16 + ((lane >> 4) << 2);
#pragma unroll
      for (int r=0;r<4;r++){
        int u = ubase + r;
        if (u < U_)
          out[((size_t)bt*U_ + u)*O_ + o] = acc[m][n][r] + bias;
      }
    }
  }
}

extern "C" void kernel_launch(void* const* d_in, const int* in_sizes, int n_in,
                              void* d_out, int out_size, void* d_ws, size_t ws_size,
                              hipStream_t stream) {
  const float* hs       = (const float*)d_in[0];
  const int*   ys       = (const int*)  d_in[1];
  const int*   hlens    = (const int*)  d_in[2];
  const float* embed    = (const float*)d_in[3];
  const float* W_ih0    = (const float*)d_in[4];
  const float* b_ih0    = (const float*)d_in[5];
  const float* W_hh0    = (const float*)d_in[6];
  const float* b_hh0    = (const float*)d_in[7];
  const float* W_ih1    = (const float*)d_in[8];
  const float* b_ih1    = (const float*)d_in[9];
  const float* W_hh1    = (const float*)d_in[10];
  const float* b_hh1    = (const float*)d_in[11];
  const float* W_att_enc= (const float*)d_in[12];
  const float* b_att_enc= (const float*)d_in[13];
  const float* W_att_dec= (const float*)d_in[14];
  const float* gvec     = (const float*)d_in[15];
  const float* W_lin_enc= (const float*)d_in[16];
  const float* b_lin_enc= (const float*)d_in[17];
  const float* W_lin_dec= (const float*)d_in[18];
  const float* W_lin_out= (const float*)d_in[19];
  const float* b_lin_out= (const float*)d_in[20];
  float* out = (float*)d_out;

  float* w = (float*)d_ws;
  // ws layout (float offsets)
  float* z0      = w;              // 2048
  float* z1      = w + 2048;       // 2048
  float* q       = w + 4096;       // 2048
  float* e       = w + 6144;       // 1024
  int*   bar     = (int*)(w + 7168); // 64 reserved
  float* eys     = w + 7232;       // 245760
  float* pre_enc = w + 252992;     // 512000
  float* pre0    = w + 764992;     // 983040
  float* henc    = w + 1748032;    // 512000
  float* h_dec   = w + 2260032;    // 245760
  float* hdec_p  = w + 2505792;    // 245760
  float* hsW0    = w + 2751552;    // 2048000 -> 4799552
  unsigned short* Pbf = (unsigned short*)(w + 4799552);            // 61,440,000 bf16
  unsigned short* Wbf = (unsigned short*)(w + 4799552 + 30720000); // 524,288 bf16
  const size_t ws_needed = (size_t)(4799552 + 30720000 + 262144) * 4;

  barinit_k<<<1, 64, 0, stream>>>(bar);
  gather_embed_k<<<(B_*U_*D_ + 255)/256, 256, 0, stream>>>(ys, embed, eys);
  // pre_enc = hs @ W_att_enc + b (nn)
  gemm64_nn_k<<<dim3(8, 16), 256, 0, stream>>>(hs, 512, W_att_enc, 512, b_att_enc,
                                               pre_enc, 512, B_*T_, 512, 512);
  // pre0 = eys @ W_ih0[:, :512]^T
  gemm64_nt_k<<<dim3(32, 8), 256, 0, stream>>>(eys, 512, W_ih0, 1024, nullptr,
                                               pre0, 2048, B_*U_, 2048, 512);
  // hsW0 = hs @ W_ih0[:, 512:]^T
  gemm64_nt_k<<<dim3(32, 16), 256, 0, stream>>>(hs, 512, W_ih0 + 512, 1024, nullptr,
                                                hsW0, 2048, B_*T_, 2048, 512);
  // henc = hs @ W_lin_enc^T + b
  gemm64_nt_k<<<dim3(8, 16), 256, 0, stream>>>(hs, 512, W_lin_enc, 512, b_lin_enc,
                                               henc, 512, B_*T_, 512, 512);

  // LDS-resident scan (cooperative launch for co-residency; own barrier inside)
  {
    void* args[] = {
      (void*)&z0, (void*)&z1, (void*)&q, (void*)&e, (void*)&bar,
      (void*)&pre_enc, (void*)&pre0, (void*)&hsW0,
      (void*)&W_hh0, (void*)&W_ih1, (void*)&W_hh1, (void*)&W_att_dec,
      (void*)&gvec, (void*)&hlens,
      (void*)&b_ih0, (void*)&b_hh0, (void*)&b_ih1, (void*)&b_hh1,
      (void*)&h_dec
    };
    hipLaunchCooperativeKernel((const void*)scan_k, dim3(NBLK), dim3(256),
                               args, 0, stream);
  }

  // hdec = h_dec @ W_lin_dec^T
  gemm64_nt_k<<<dim3(8, 8), 256, 0, stream>>>(h_dec, 512, W_lin_dec, 512, nullptr,
                                              hdec_p, 512, B_*U_, 512, 512);
  if (ws_size >= ws_needed){
    tanh_pack_k<<<(B_*T_*U_*512/8 + 255)/256, 256, 0, stream>>>(henc, hdec_p, Pbf);
    wconv_k<<<(O_*512/8 + 255)/256, 256, 0, stream>>>(W_lin_out, Wbf, O_*512/8);
    joint_mfma_k<<<dim3(8, T_, B_), 256, 0, stream>>>(Pbf, Wbf, b_lin_out, out);
  } else {
    joint_k<<<dim3(8, T_, B_), 256, 0, stream>>>(henc, hdec_p, W_lin_out, b_lin_out, out);
  }
}

// Round 6
// 3063.259 us; speedup vs baseline: 4.5654x; 1.3535x over previous
//
#include <hip/hip_runtime.h>

#define B_ 4
#define T_ 250
#define U_ 120
#define D_ 512
#define G_ 2048   // 4*D (gates)
#define O_ 1024   // odim
#define NBLK 256

typedef __attribute__((ext_vector_type(8))) short bf16x8;
typedef __attribute__((ext_vector_type(4))) float f32x4;
typedef __attribute__((ext_vector_type(4))) unsigned int ui4;

__device__ __forceinline__ float tanh_fast(float x){
  float e = __expf(2.f*x);
  return 1.f - 2.f/(e + 1.f);
}
__device__ __forceinline__ float sigmoid_fast(float x){
  return 1.f/(1.f + __expf(-x));
}
__device__ __forceinline__ unsigned short f2bf(float x){
  unsigned int u = __float_as_uint(x);
  unsigned int r = (u + 0x7FFFu + ((u >> 16) & 1u)) >> 16;
  return (unsigned short)r;
}

// MALL-coherent data exchange (no cache flush)
__device__ __forceinline__ float atomLoadF(const float* p){
  return __hip_atomic_load(p, __ATOMIC_RELAXED, __HIP_MEMORY_SCOPE_AGENT);
}
__device__ __forceinline__ void atomStoreF(float* p, float v){
  __hip_atomic_store(p, v, __ATOMIC_RELAXED, __HIP_MEMORY_SCOPE_AGENT);
}

// distributed-flag grid barrier: flags[bk*16], one 64B line per block.
// Arrival store is contention-free; every thread polls one block's flag.
__device__ __forceinline__ void gbar(int* flags, int gen){
  __syncthreads();   // drains vmcnt(0) per wave before s_barrier
  if (threadIdx.x == 0){
    asm volatile("s_waitcnt vmcnt(0)" ::: "memory");
    __hip_atomic_store(&flags[blockIdx.x*16], gen, __ATOMIC_RELAXED,
                       __HIP_MEMORY_SCOPE_AGENT);
  }
  {
    long c = 0;
    while (__hip_atomic_load(&flags[threadIdx.x*16], __ATOMIC_RELAXED,
                             __HIP_MEMORY_SCOPE_AGENT) < gen){
      if (++c > (1L<<24)) break;   // anti-hang valve
    }
  }
  __syncthreads();
}

__global__ void barinit_k(int* flags){
  int i = blockIdx.x*256 + threadIdx.x;
  if (i < NBLK*16)
    __hip_atomic_store(&flags[i], 0, __ATOMIC_RELAXED, __HIP_MEMORY_SCOPE_AGENT);
}

__global__ void gather_embed_k(const int* __restrict__ ys, const float* __restrict__ embed,
                               float* __restrict__ eys){
  int i = blockIdx.x*256 + threadIdx.x;
  if (i < B_*U_*D_){
    int r = i >> 9, k = i & 511;
    eys[i] = embed[ys[r]*D_ + k];
  }
}

// ---------- 64x64-tile f32 GEMMs for precompute ----------
__global__ __launch_bounds__(256) void gemm64_nt_k(
  const float* __restrict__ A, int lda, const float* __restrict__ B, int ldb,
  const float* __restrict__ bias, float* __restrict__ C, int ldc,
  int M, int N, int K)
{
  __shared__ float As[16][65], Bs[16][65];
  int tid = threadIdx.x;
  int m0 = blockIdx.y*64, n0 = blockIdx.x*64;
  int tx = tid & 15, ty = tid >> 4;
  float acc[4][4] = {};
  for (int k0 = 0; k0 < K; k0 += 16){
#pragma unroll
    for (int i=0;i<4;i++){
      int e = tid + 256*i;
      int mm = e >> 4, kk = e & 15;
      int mg = m0 + mm;
      As[kk][mm] = (mg < M) ? A[(size_t)mg*lda + k0 + kk] : 0.f;
      int ng = n0 + mm;
      Bs[kk][mm] = (ng < N) ? B[(size_t)ng*ldb + k0 + kk] : 0.f;
    }
    __syncthreads();
#pragma unroll
    for (int kk=0;kk<16;kk++){
      float av[4], bv[4];
#pragma unroll
      for (int i=0;i<4;i++) av[i] = As[kk][ty*4+i];
#pragma unroll
      for (int j=0;j<4;j++) bv[j] = Bs[kk][tx*4+j];
#pragma unroll
      for (int i=0;i<4;i++)
#pragma unroll
        for (int j=0;j<4;j++) acc[i][j] += av[i]*bv[j];
    }
    __syncthreads();
  }
#pragma unroll
  for (int i=0;i<4;i++){
    int m = m0 + ty*4 + i;
    if (m < M){
#pragma unroll
      for (int j=0;j<4;j++){
        int n = n0 + tx*4 + j;
        if (n < N) C[(size_t)m*ldc + n] = acc[i][j] + (bias ? bias[n] : 0.f);
      }
    }
  }
}

__global__ __launch_bounds__(256) void gemm64_nn_k(
  const float* __restrict__ A, int lda, const float* __restrict__ B, int ldb,
  const float* __restrict__ bias, float* __restrict__ C, int ldc,
  int M, int N, int K)
{
  __shared__ float As[16][65], Bs[16][65];
  int tid = threadIdx.x;
  int m0 = blockIdx.y*64, n0 = blockIdx.x*64;
  int tx = tid & 15, ty = tid >> 4;
  float acc[4][4] = {};
  for (int k0 = 0; k0 < K; k0 += 16){
#pragma unroll
    for (int i=0;i<4;i++){
      int e = tid + 256*i;
      int mm = e >> 4, kk = e & 15;
      int mg = m0 + mm;
      As[kk][mm] = (mg < M) ? A[(size_t)mg*lda + k0 + kk] : 0.f;
      int nn = e & 63, kk2 = e >> 6;
      int ng = n0 + nn;
      Bs[kk2][nn] = (ng < N) ? B[(size_t)(k0+kk2)*ldb + ng] : 0.f;
    }
    __syncthreads();
#pragma unroll
    for (int kk=0;kk<16;kk++){
      float av[4], bv[4];
#pragma unroll
      for (int i=0;i<4;i++) av[i] = As[kk][ty*4+i];
#pragma unroll
      for (int j=0;j<4;j++) bv[j] = Bs[kk][tx*4+j];
#pragma unroll
      for (int i=0;i<4;i++)
#pragma unroll
        for (int j=0;j<4;j++) acc[i][j] += av[i]*bv[j];
    }
    __syncthreads();
  }
#pragma unroll
  for (int i=0;i<4;i++){
    int m = m0 + ty*4 + i;
    if (m < M){
#pragma unroll
      for (int j=0;j<4;j++){
        int n = n0 + tx*4 + j;
        if (n < N) C[(size_t)m*ldc + n] = acc[i][j] + (bias ? bias[n] : 0.f);
      }
    }
  }
}

// ---------- LDS-resident scan with distributed-flag barrier ----------
// 256 blocks x 256 threads. Block bk owns d = {2bk, 2bk+1}. All weights in LDS.
__global__ __launch_bounds__(256) void scan_k(
    float* __restrict__ z0, float* __restrict__ z1,
    float* __restrict__ q,  float* __restrict__ e, int* __restrict__ flags,
    const float* __restrict__ pre_enc, const float* __restrict__ pre0,
    const float* __restrict__ hsW0,
    const float* __restrict__ W_hh0, const float* __restrict__ W_ih1,
    const float* __restrict__ W_hh1, const float* __restrict__ W_att_dec,
    const float* __restrict__ gvec, const int* __restrict__ hlens,
    const float* __restrict__ b_ih0, const float* __restrict__ b_hh0,
    const float* __restrict__ b_ih1, const float* __restrict__ b_hh1,
    float* __restrict__ h_dec)
{
  int bk = blockIdx.x, tid = threadIdx.x;
  int lane = tid & 63, wv = tid >> 6;
  int d0 = bk * 2;

  __shared__ float whh0_s[8*512];   // [gd][k]
  __shared__ float whh1_s[8*512];
  __shared__ float wih1_s[8*512];
  __shared__ float wdec_s[2*512];   // [delta][k]
  __shared__ float hsw_s[4*8*256];  // [b][gd][t(pad 256)]
  __shared__ float pre0_s[480*8];   // [(b*120+u)][gd]
  __shared__ float pre_s[4*512];    // e-rows
  __shared__ float gvec_s[512];
  __shared__ float zs0[2048], zs1[2048], qs[2048];
  __shared__ float pA0[32], pA1[32], gB[32], gC[32];
  __shared__ float bias0_s[8], bias1_s[8], c0_s[8], c1_s[8];
  __shared__ int hlens_s[4];

  // ---- one-time LDS load (coalesced rows from original j-major weights) ----
  for (int idx = tid; idx < 8*512; idx += 256){
    int gd = idx >> 9, k = idx & 511;
    int j = (gd >> 1)*512 + d0 + (gd & 1);
    whh0_s[idx] = W_hh0[(size_t)j*512 + k];
    whh1_s[idx] = W_hh1[(size_t)j*512 + k];
    wih1_s[idx] = W_ih1[(size_t)j*512 + k];
  }
  for (int idx = tid; idx < 2*512; idx += 256){
    int dd = idx >> 9, k = idx & 511;
    wdec_s[idx] = W_att_dec[(size_t)k*512 + d0 + dd];
  }
  for (int idx = tid; idx < 4*1000; idx += 256){
    int gp = idx & 3, tg = idx >> 2;
    int b = tg / 250, t = tg - b*250;
    const float2 v = *(const float2*)(hsW0 + (size_t)tg*G_ + gp*512 + d0);
    hsw_s[(b*8 + gp*2 + 0)*256 + t] = v.x;
    hsw_s[(b*8 + gp*2 + 1)*256 + t] = v.y;
  }
  for (int idx = tid; idx < 4*8*6; idx += 256){   // zero t-pad 250..255
    int t = 250 + (idx % 6), bg = idx / 6;
    hsw_s[bg*256 + t] = 0.f;
  }
  for (int idx = tid; idx < 480*4; idx += 256){
    int gp = idx & 3, r = idx >> 2;
    const float2 v = *(const float2*)(pre0 + (size_t)r*G_ + gp*512 + d0);
    pre0_s[r*8 + gp*2 + 0] = v.x;
    pre0_s[r*8 + gp*2 + 1] = v.y;
  }
  for (int idx = tid; idx < 4*512; idx += 256){
    int r = bk*4 + (idx >> 9);
    pre_s[idx] = (r < B_*T_) ? pre_enc[(size_t)r*512 + (idx & 511)] : 0.f;
  }
  for (int idx = tid; idx < 512; idx += 256) gvec_s[idx] = gvec[idx];
  if (tid < 4) hlens_s[tid] = hlens[tid];
  if (tid < 8){
    int j = ((tid >> 1))*512 + d0 + (tid & 1);
    bias0_s[tid] = b_ih0[j] + b_hh0[j];
    bias1_s[tid] = b_ih1[j] + b_hh1[j];
    c0_s[tid] = 0.f; c1_s[tid] = 0.f;
    int b = tid >> 1, d = d0 + (tid & 1);
    atomStoreF(&z0[b*512 + d], 0.f);
    atomStoreF(&z1[b*512 + d], 0.f);
    atomStoreF(&q [b*512 + d], 0.f);
  }
  int gen = 0;
  gbar(flags, ++gen);

  for (int u = 0; u < U_; ++u){
    // ---------------- Phase A ----------------
    for (int i = tid; i < 2048; i += 256){
      zs0[i] = atomLoadF(&z0[i]);
      zs1[i] = atomLoadF(&z1[i]);
      qs[i]  = atomLoadF(&q[i]);
    }
    __syncthreads();
    {
      int gd0 = wv*2, gd1 = wv*2 + 1;
      float a00[4]={}, a01[4]={}, a10[4]={}, a11[4]={};
#pragma unroll
      for (int i = 0; i < 8; ++i){
        int k = i*64 + lane;
        float w00 = whh0_s[gd0*512+k], w01 = whh0_s[gd1*512+k];
        float w10 = whh1_s[gd0*512+k], w11 = whh1_s[gd1*512+k];
#pragma unroll
        for (int b=0;b<4;b++){
          float zv0 = zs0[b*512+k], zv1 = zs1[b*512+k];
          a00[b] += w00*zv0; a01[b] += w01*zv0;
          a10[b] += w10*zv1; a11[b] += w11*zv1;
        }
      }
#pragma unroll
      for (int b=0;b<4;b++){
#pragma unroll
        for (int off=32; off; off>>=1){
          a00[b] += __shfl_xor(a00[b],off); a01[b] += __shfl_xor(a01[b],off);
          a10[b] += __shfl_xor(a10[b],off); a11[b] += __shfl_xor(a11[b],off);
        }
      }
      if (lane == 0){
#pragma unroll
        for (int b=0;b<4;b++){
          pA0[b*8+gd0] = a00[b]; pA0[b*8+gd1] = a01[b];
          pA1[b*8+gd0] = a10[b]; pA1[b*8+gd1] = a11[b];
        }
      }
    }
    {
      int r = bk*4 + wv;
      if (r < B_*T_){
        int b = r / 250, t = r - b*250;
        float s = 0.f;
#pragma unroll
        for (int i=0;i<8;i++){
          int k = i*64 + lane;
          float x = pre_s[wv*512+k] + qs[b*512+k];
          s += tanh_fast(x) * gvec_s[k];
        }
#pragma unroll
        for (int off=32; off; off>>=1) s += __shfl_xor(s, off);
        if (lane == 0) atomStoreF(&e[r], (t < hlens_s[b]) ? s : -1e30f);
      }
    }
    gbar(flags, ++gen);
    // ---------------- Phase B ----------------
    {
      int b = wv;  // wave handles batch wv
      float vals[4], w_reg[4];
      float vmax = -1e30f;
#pragma unroll
      for (int i=0;i<4;i++){
        int t = i*64 + lane;
        vals[i] = (t < 250) ? atomLoadF(&e[b*250 + t]) : -1e30f;
        vmax = fmaxf(vmax, vals[i]);
      }
#pragma unroll
      for (int off=32; off; off>>=1) vmax = fmaxf(vmax, __shfl_xor(vmax, off));
      float ssum = 0.f;
#pragma unroll
      for (int i=0;i<4;i++){
        int t = i*64 + lane;
        w_reg[i] = (t < 250) ? __expf(vals[i] - vmax) : 0.f;
        ssum += w_reg[i];
      }
#pragma unroll
      for (int off=32; off; off>>=1) ssum += __shfl_xor(ssum, off);
      float inv = 1.f / ssum;
#pragma unroll
      for (int i=0;i<4;i++) w_reg[i] *= inv;

      float ag[8] = {};
#pragma unroll
      for (int i=0;i<4;i++){
        int t = i*64 + lane;
#pragma unroll
        for (int gd=0; gd<8; gd++)
          ag[gd] += w_reg[i] * hsw_s[(b*8+gd)*256 + t];
      }
#pragma unroll
      for (int gd=0; gd<8; gd++){
#pragma unroll
        for (int off=32; off; off>>=1) ag[gd] += __shfl_xor(ag[gd], off);
      }
      if (lane == 0){
#pragma unroll
        for (int gd=0; gd<8; gd++)
          gB[b*8+gd] = ag[gd] + pA0[b*8+gd] + pre0_s[(b*U_+u)*8 + gd] + bias0_s[gd];
      }
    }
    __syncthreads();
    if (tid < 8){
      int b = tid >> 1, dd = tid & 1;
      float ig = sigmoid_fast(gB[b*8 + 0 + dd]);
      float fg = sigmoid_fast(gB[b*8 + 2 + dd]);
      float gg = tanh_fast  (gB[b*8 + 4 + dd]);
      float og = sigmoid_fast(gB[b*8 + 6 + dd]);
      float cn = fg * c0_s[tid] + ig * gg;
      c0_s[tid] = cn;
      atomStoreF(&z0[b*512 + d0 + dd], og * tanh_fast(cn));
    }
    gbar(flags, ++gen);
    // ---------------- Phase C ----------------
    for (int i = tid; i < 2048; i += 256) zs0[i] = atomLoadF(&z0[i]);
    __syncthreads();
    {
      int gd0 = wv*2, gd1 = wv*2 + 1;
      float a0[4]={}, a1[4]={};
#pragma unroll
      for (int i=0;i<8;i++){
        int k = i*64 + lane;
        float w0 = wih1_s[gd0*512+k], w1 = wih1_s[gd1*512+k];
#pragma unroll
        for (int b=0;b<4;b++){
          float zv = zs0[b*512+k];
          a0[b] += w0*zv; a1[b] += w1*zv;
        }
      }
#pragma unroll
      for (int b=0;b<4;b++){
#pragma unroll
        for (int off=32; off; off>>=1){
          a0[b] += __shfl_xor(a0[b],off); a1[b] += __shfl_xor(a1[b],off);
        }
      }
      if (lane == 0){
#pragma unroll
        for (int b=0;b<4;b++){
          gC[b*8+gd0] = a0[b] + pA1[b*8+gd0] + bias1_s[gd0];
          gC[b*8+gd1] = a1[b] + pA1[b*8+gd1] + bias1_s[gd1];
        }
      }
      if (wv < 2){
        float qa[4] = {};
#pragma unroll
        for (int i=0;i<8;i++){
          int k = i*64 + lane;
          float wq = wdec_s[wv*512+k];
#pragma unroll
          for (int b=0;b<4;b++) qa[b] += wq * zs0[b*512+k];
        }
#pragma unroll
        for (int b=0;b<4;b++){
#pragma unroll
          for (int off=32; off; off>>=1) qa[b] += __shfl_xor(qa[b],off);
        }
        if (lane == 0){
#pragma unroll
          for (int b=0;b<4;b++) atomStoreF(&q[b*512 + d0 + wv], qa[b]);
        }
      }
    }
    __syncthreads();
    if (tid < 8){
      int b = tid >> 1, dd = tid & 1;
      float ig = sigmoid_fast(gC[b*8 + 0 + dd]);
      float fg = sigmoid_fast(gC[b*8 + 2 + dd]);
      float gg = tanh_fast  (gC[b*8 + 4 + dd]);
      float og = sigmoid_fast(gC[b*8 + 6 + dd]);
      float cn = fg * c1_s[tid] + ig * gg;
      c1_s[tid] = cn;
      float hn = og * tanh_fast(cn);
      atomStoreF(&z1[b*512 + d0 + dd], hn);
      h_dec[((size_t)(b*U_ + u))*512 + d0 + dd] = hn;   // ordinary; read post-kernel
    }
    gbar(flags, ++gen);
  }
}

// ---------- fallback f32 joint ----------
#define JKC 16
__global__ __launch_bounds__(256) void joint_k(
    const float* __restrict__ henc, const float* __restrict__ hdec,
    const float* __restrict__ Wout, const float* __restrict__ bout,
    float* __restrict__ out)
{
  int ot = blockIdx.x;
  int t  = blockIdx.y;
  int b  = blockIdx.z;
  __shared__ float As[128][JKC+1];
  __shared__ float Bs[128][JKC+1];
  int tid = threadIdx.x;
  int tx = tid & 15, ty = tid >> 4;
  float acc[8][8] = {};
  const float* henc_row = henc + (size_t)(b*T_ + t)*512;
  for (int k0 = 0; k0 < 512; k0 += JKC){
#pragma unroll
    for (int i=0;i<8;i++){
      int e = tid*8+i; int r = e>>4, kk = e&15;
      float hv = henc_row[k0+kk];
      float dv = (r < U_) ? hdec[(size_t)(b*U_ + r)*512 + k0 + kk] : 0.f;
      As[r][kk] = tanh_fast(hv+dv);
      Bs[r][kk] = Wout[(size_t)(ot*128 + r)*512 + k0 + kk];
    }
    __syncthreads();
#pragma unroll
    for (int kk=0; kk<JKC; kk++){
      float a[8], bb[8];
#pragma unroll
      for (int i=0;i<8;i++) a[i]  = As[ty*8+i][kk];
#pragma unroll
      for (int j=0;j<8;j++) bb[j] = Bs[tx*8+j][kk];
#pragma unroll
      for (int i=0;i<8;i++)
#pragma unroll
        for (int j=0;j<8;j++)
          acc[i][j] += a[i]*bb[j];
    }
    __syncthreads();
  }
  int o0 = ot*128 + tx*8;
#pragma unroll
  for (int i=0;i<8;i++){
    int u = ty*8 + i;
    if (u < U_){
      float* op = out + ((size_t)(b*T_ + t)*U_ + u)*O_ + o0;
#pragma unroll
      for (int j=0;j<8;j++) op[j] = acc[i][j] + bout[o0+j];
    }
  }
}

// ---------- bf16 MFMA joint path ----------
__global__ __launch_bounds__(256) void tanh_pack_k(
    const float* __restrict__ henc, const float* __restrict__ hdec,
    unsigned short* __restrict__ P)
{
  int i = blockIdx.x*256 + threadIdx.x;
  if (i >= B_*T_*U_*512/8) return;
  int e = i*8;
  int k = e & 511;
  int r = e >> 9;
  int u = r % U_;
  int bt = r / U_;
  int b = bt / T_;
  const float* hp = henc + (size_t)bt*512 + k;
  const float* dp = hdec + (size_t)(b*U_ + u)*512 + k;
  unsigned int w[4];
#pragma unroll
  for (int j=0;j<4;j++){
    unsigned short lo = f2bf(tanh_fast(hp[2*j]   + dp[2*j]));
    unsigned short hi = f2bf(tanh_fast(hp[2*j+1] + dp[2*j+1]));
    w[j] = (unsigned int)lo | ((unsigned int)hi << 16);
  }
  ui4* dst = (ui4*)(P + e);
  *dst = ui4{w[0], w[1], w[2], w[3]};
}

__global__ __launch_bounds__(256) void wconv_k(const float* __restrict__ W,
                                               unsigned short* __restrict__ Wb, int n8){
  int i = blockIdx.x*256 + threadIdx.x;
  if (i >= n8) return;
  int e = i*8;
  unsigned int w[4];
#pragma unroll
  for (int j=0;j<4;j++){
    unsigned short lo = f2bf(W[e+2*j]);
    unsigned short hi = f2bf(W[e+2*j+1]);
    w[j] = (unsigned int)lo | ((unsigned int)hi << 16);
  }
  *(ui4*)(Wb + e) = ui4{w[0], w[1], w[2], w[3]};
}

__global__ __launch_bounds__(256) void joint_mfma_k(
    const unsigned short* __restrict__ P,
    const unsigned short* __restrict__ Wb,
    const float* __restrict__ bout,
    float* __restrict__ out)
{
  __shared__ unsigned short As[128*64];
  __shared__ unsigned short Bs[128*64];
  int tid = threadIdx.x;
  int lane = tid & 63;
  int w = tid >> 6, wr = w >> 1, wc = w & 1;
  int o0 = blockIdx.x * 128;
  int t = blockIdx.y, b = blockIdx.z;
  int bt = b*T_ + t;
  const char* Pbase = (const char*)(P + (size_t)bt*U_*512);
  const char* Wbase = (const char*)(Wb + (size_t)o0*512);

  f32x4 acc[4][4] = {};

  for (int k0 = 0; k0 < 512; k0 += 64){
    __syncthreads();
#pragma unroll
    for (int j=0;j<4;j++){
      int pos = (j*256 + tid)*16;
      int row = pos >> 7;
      int inrow = pos & 127;
      int srcin = inrow ^ ((row & 7) << 4);
      int arow = row < U_ ? row : (U_-1);
      __builtin_amdgcn_global_load_lds(
        (const __attribute__((address_space(1))) void*)(Pbase + (size_t)arow*1024 + k0*2 + srcin),
        (__attribute__((address_space(3))) void*)((char*)As + pos), 16, 0, 0);
      __builtin_amdgcn_global_load_lds(
        (const __attribute__((address_space(1))) void*)(Wbase + (size_t)row*1024 + k0*2 + srcin),
        (__attribute__((address_space(3))) void*)((char*)Bs + pos), 16, 0, 0);
    }
    __syncthreads();
#pragma unroll
    for (int kk=0; kk<2; kk++){
      bf16x8 a[4], bb[4];
#pragma unroll
      for (int m=0;m<4;m++){
        int row = wr*64 + m*16 + (lane & 15);
        int inrow = (kk*64 + (lane >> 4)*16) ^ ((row & 7) << 4);
        a[m] = *(const bf16x8*)((const char*)As + row*128 + inrow);
      }
#pragma unroll
      for (int n=0;n<4;n++){
        int row = wc*64 + n*16 + (lane & 15);
        int inrow = (kk*64 + (lane >> 4)*16) ^ ((row & 7) << 4);
        bb[n] = *(const bf16x8*)((const char*)Bs + row*128 + inrow);
      }
#pragma unroll
      for (int m=0;m<4;m++)
#pragma unroll
        for (int n=0;n<4;n++)
          acc[m][n] = __builtin_amdgcn_mfma_f32_16x16x32_bf16(a[m], bb[n], acc[m][n], 0, 0, 0);
    }
  }
#pragma unroll
  for (int n=0;n<4;n++){
    int o = o0 + wc*64 + n*16 + (lane & 15);
    float bias = bout[o];
#pragma unroll
    for (int m=0;m<4;m++){
      int ubase = wr*64 + m*16 + ((lane >> 4) << 2);
#pragma unroll
      for (int r=0;r<4;r++){
        int u = ubase + r;
        if (u < U_)
          out[((size_t)bt*U_ + u)*O_ + o] = acc[m][n][r] + bias;
      }
    }
  }
}

extern "C" void kernel_launch(void* const* d_in, const int* in_sizes, int n_in,
                              void* d_out, int out_size, void* d_ws, size_t ws_size,
                              hipStream_t stream) {
  const float* hs       = (const float*)d_in[0];
  const int*   ys       = (const int*)  d_in[1];
  const int*   hlens    = (const int*)  d_in[2];
  const float* embed    = (const float*)d_in[3];
  const float* W_ih0    = (const float*)d_in[4];
  const float* b_ih0    = (const float*)d_in[5];
  const float* W_hh0    = (const float*)d_in[6];
  const float* b_hh0    = (const float*)d_in[7];
  const float* W_ih1    = (const float*)d_in[8];
  const float* b_ih1    = (const float*)d_in[9];
  const float* W_hh1    = (const float*)d_in[10];
  const float* b_hh1    = (const float*)d_in[11];
  const float* W_att_enc= (const float*)d_in[12];
  const float* b_att_enc= (const float*)d_in[13];
  const float* W_att_dec= (const float*)d_in[14];
  const float* gvec     = (const float*)d_in[15];
  const float* W_lin_enc= (const float*)d_in[16];
  const float* b_lin_enc= (const float*)d_in[17];
  const float* W_lin_dec= (const float*)d_in[18];
  const float* W_lin_out= (const float*)d_in[19];
  const float* b_lin_out= (const float*)d_in[20];
  float* out = (float*)d_out;

  float* w = (float*)d_ws;
  // ws layout (float offsets)
  float* z0      = w;              // 2048
  float* z1      = w + 2048;       // 2048
  float* q       = w + 4096;       // 2048
  float* e       = w + 6144;       // 1024
  int*   flags   = (int*)(w + 7168); // 4096 ints (256 x 64B lines)
  float* eys     = w + 11264;      // 245760
  float* pre_enc = w + 257024;     // 512000
  float* pre0    = w + 769024;     // 983040
  float* henc    = w + 1752064;    // 512000
  float* h_dec   = w + 2264064;    // 245760
  float* hdec_p  = w + 2509824;    // 245760
  float* hsW0    = w + 2755584;    // 2048000 -> 4803584
  unsigned short* Pbf = (unsigned short*)(w + 4803584);            // 61,440,000 bf16
  unsigned short* Wbf = (unsigned short*)(w + 4803584 + 30720000); // 524,288 bf16
  const size_t ws_needed = (size_t)(4803584 + 30720000 + 262144) * 4;

  barinit_k<<<16, 256, 0, stream>>>(flags);
  gather_embed_k<<<(B_*U_*D_ + 255)/256, 256, 0, stream>>>(ys, embed, eys);
  // pre_enc = hs @ W_att_enc + b (nn)
  gemm64_nn_k<<<dim3(8, 16), 256, 0, stream>>>(hs, 512, W_att_enc, 512, b_att_enc,
                                               pre_enc, 512, B_*T_, 512, 512);
  // pre0 = eys @ W_ih0[:, :512]^T
  gemm64_nt_k<<<dim3(32, 8), 256, 0, stream>>>(eys, 512, W_ih0, 1024, nullptr,
                                               pre0, 2048, B_*U_, 2048, 512);
  // hsW0 = hs @ W_ih0[:, 512:]^T
  gemm64_nt_k<<<dim3(32, 16), 256, 0, stream>>>(hs, 512, W_ih0 + 512, 1024, nullptr,
                                                hsW0, 2048, B_*T_, 2048, 512);
  // henc = hs @ W_lin_enc^T + b
  gemm64_nt_k<<<dim3(8, 16), 256, 0, stream>>>(hs, 512, W_lin_enc, 512, b_lin_enc,
                                               henc, 512, B_*T_, 512, 512);

  // LDS-resident scan (cooperative launch for co-residency; own barrier inside)
  {
    void* args[] = {
      (void*)&z0, (void*)&z1, (void*)&q, (void*)&e, (void*)&flags,
      (void*)&pre_enc, (void*)&pre0, (void*)&hsW0,
      (void*)&W_hh0, (void*)&W_ih1, (void*)&W_hh1, (void*)&W_att_dec,
      (void*)&gvec, (void*)&hlens,
      (void*)&b_ih0, (void*)&b_hh0, (void*)&b_ih1, (void*)&b_hh1,
      (void*)&h_dec
    };
    hipLaunchCooperativeKernel((const void*)scan_k, dim3(NBLK), dim3(256),
                               args, 0, stream);
  }

  // hdec = h_dec @ W_lin_dec^T
  gemm64_nt_k<<<dim3(8, 8), 256, 0, stream>>>(h_dec, 512, W_lin_dec, 512, nullptr,
                                              hdec_p, 512, B_*U_, 512, 512);
  if (ws_size >= ws_needed){
    tanh_pack_k<<<(B_*T_*U_*512/8 + 255)/256, 256, 0, stream>>>(henc, hdec_p, Pbf);
    wconv_k<<<(O_*512/8 + 255)/256, 256, 0, stream>>>(W_lin_out, Wbf, O_*512/8);
    joint_mfma_k<<<dim3(8, T_, B_), 256, 0, stream>>>(Pbf, Wbf, b_lin_out, out);
  } else {
    joint_k<<<dim3(8, T_, B_), 256, 0, stream>>>(henc, hdec_p, W_lin_out, b_lin_out, out);
  }
}